// Round 4
// baseline (757.906 us; speedup 1.0000x reference)
//
#include <hip/hip_runtime.h>

#define NN 50000
#define NE 1600000
#define IND 256
#define OUTD 64
#define NH 4

// ---- build Wc[k][i*64+d] = W[i][k][d] (256x256) ----
__global__ __launch_bounds__(256) void k_wc(const float* __restrict__ W, float* __restrict__ Wc) {
    int t = blockIdx.x * 256 + threadIdx.x;   // 0..65535
    int k = t >> 8, c = t & 255;
    int i = c >> 6, d = c & 63;
    Wc[t] = W[i * IND * OUTD + k * OUTD + d];
}

// ---- z[N][256] = (h*norm) @ Wc, 64x64 tiles, 4x4 per thread ----
__global__ __launch_bounds__(256) void k_gemm(const float* __restrict__ h, const float* __restrict__ norm,
                                              const float* __restrict__ Wc, float* __restrict__ z) {
    __shared__ float As[64][65];
    __shared__ float Bs[64][65];
    const int bm = blockIdx.x * 64;
    const int bn = blockIdx.y * 64;
    const int tid = threadIdx.x;
    const int tx = tid & 15, ty = tid >> 4;
    float acc[4][4] = {};
    for (int k0 = 0; k0 < IND; k0 += 64) {
        #pragma unroll
        for (int t = 0; t < 16; ++t) {
            int idx = t * 256 + tid;
            int m = idx >> 6, kk = idx & 63;
            int gr = bm + m;
            float av = 0.f;
            if (gr < NN) av = h[gr * IND + k0 + kk] * norm[gr];
            As[m][kk] = av;
            Bs[m][kk] = Wc[(k0 + m) * IND + bn + kk];   // row m of B-tile, col kk
        }
        __syncthreads();
        #pragma unroll 8
        for (int kk = 0; kk < 64; ++kk) {
            float a0 = As[ty * 4 + 0][kk];
            float a1 = As[ty * 4 + 1][kk];
            float a2 = As[ty * 4 + 2][kk];
            float a3 = As[ty * 4 + 3][kk];
            float b0 = Bs[kk][tx * 4 + 0];
            float b1 = Bs[kk][tx * 4 + 1];
            float b2 = Bs[kk][tx * 4 + 2];
            float b3 = Bs[kk][tx * 4 + 3];
            acc[0][0] += a0 * b0; acc[0][1] += a0 * b1; acc[0][2] += a0 * b2; acc[0][3] += a0 * b3;
            acc[1][0] += a1 * b0; acc[1][1] += a1 * b1; acc[1][2] += a1 * b2; acc[1][3] += a1 * b3;
            acc[2][0] += a2 * b0; acc[2][1] += a2 * b1; acc[2][2] += a2 * b2; acc[2][3] += a2 * b3;
            acc[3][0] += a3 * b0; acc[3][1] += a3 * b1; acc[3][2] += a3 * b2; acc[3][3] += a3 * b3;
        }
        __syncthreads();
    }
    #pragma unroll
    for (int r = 0; r < 4; ++r) {
        int gr = bm + ty * 4 + r;
        if (gr < NN) {
            #pragma unroll
            for (int c = 0; c < 4; ++c)
                z[gr * IND + bn + tx * 4 + c] = acc[r][c];
        }
    }
}

// ---- per-node score halves: s_src[n][i] = z[n,i,:]·a[i,:64], s_dst = ·a[i,64:] ----
__global__ __launch_bounds__(256) void k_stab(const float* __restrict__ z, const float* __restrict__ a,
                                              float* __restrict__ ssrc, float* __restrict__ sdst) {
    int wv = threadIdx.x >> 6, lane = threadIdx.x & 63;
    int n = blockIdx.x * 4 + wv;
    if (n >= NN) return;
    #pragma unroll
    for (int i = 0; i < NH; ++i) {
        float v = z[n * IND + i * OUTD + lane];
        float ps = v * a[i * 128 + lane];
        float pd = v * a[i * 128 + 64 + lane];
        for (int off = 32; off > 0; off >>= 1) {
            ps += __shfl_down(ps, off);
            pd += __shfl_down(pd, off);
        }
        if (lane == 0) { ssrc[n * NH + i] = ps; sdst[n * NH + i] = pd; }
    }
}

// ---- CSR: histogram ----
__global__ __launch_bounds__(256) void k_hist(const int* __restrict__ dst, int* __restrict__ cnt) {
    int ed = blockIdx.x * 256 + threadIdx.x;
    if (ed < NE) atomicAdd(&cnt[dst[ed]], 1);
}

// ---- CSR: single-block exclusive scan (1024 threads, shuffle-based) ----
__global__ __launch_bounds__(1024) void k_scan(const int* __restrict__ cnt, int* __restrict__ rowp,
                                               int* __restrict__ cur) {
    __shared__ int wsum[16];
    __shared__ int s_carry;
    int tid = threadIdx.x, lane = tid & 63, w = tid >> 6;
    if (tid == 0) { s_carry = 0; rowp[NN] = 0; }
    __syncthreads();
    for (int base = 0; base < NN; base += 1024) {
        int i = base + tid;
        int v = (i < NN) ? cnt[i] : 0;
        int x = v;
        for (int off = 1; off < 64; off <<= 1) {
            int t = __shfl_up(x, off);
            if (lane >= off) x += t;
        }
        if (lane == 63) wsum[w] = x;
        __syncthreads();
        if (w == 0 && lane < 16) {
            int y = wsum[lane];
            for (int off = 1; off < 16; off <<= 1) {
                int t = __shfl_up(y, off, 16);
                if ((lane & 15) >= off) y += t;
            }
            wsum[lane] = y;   // inclusive scan of wave sums
        }
        __syncthreads();
        int waveoff = (w == 0) ? 0 : wsum[w - 1];
        int pos = s_carry + waveoff + (x - v);   // exclusive prefix
        if (i < NN) {
            rowp[i] = pos;
            cur[i] = pos;
            if (i == NN - 1) rowp[NN] = pos + v;
        }
        __syncthreads();
        if (tid == 0) s_carry += wsum[15];
        __syncthreads();
    }
}

// ---- CSR: scatter edges into dst-sorted order ----
__global__ __launch_bounds__(256) void k_scatter(const int* __restrict__ src, const int* __restrict__ dst,
                                                 int* __restrict__ cur, int* __restrict__ srcs,
                                                 int* __restrict__ dsts) {
    int ed = blockIdx.x * 256 + threadIdx.x;
    if (ed < NE) {
        int d = dst[ed];
        int p = atomicAdd(&cur[d], 1);
        srcs[p] = src[ed];
        dsts[p] = d;
    }
}

// ---- unnormalized edge weights w[p][i] = exp(s_src[srcs[p]][i] + s_dst[dsts[p]][i]) ----
__global__ __launch_bounds__(256) void k_w(const int* __restrict__ srcs, const int* __restrict__ dsts,
                                           const float4* __restrict__ ssrc4, const float4* __restrict__ sdst4,
                                           float4* __restrict__ w4) {
    int p = blockIdx.x * 256 + threadIdx.x;
    if (p < NE) {
        float4 sa = ssrc4[srcs[p]];
        float4 sb = sdst4[dsts[p]];
        float4 r;
        r.x = __expf(sa.x + sb.x);
        r.y = __expf(sa.y + sb.y);
        r.z = __expf(sa.z + sb.z);
        r.w = __expf(sa.w + sb.w);
        w4[p] = r;
    }
}

// ---- aggregation: wave per node, acc = sum_p w*z[src_p], out = h + norm*acc/den ----
__global__ __launch_bounds__(256) void k_agg(const float* __restrict__ z, const int* __restrict__ rowp,
                                             const int* __restrict__ srcs, const float4* __restrict__ w4,
                                             const float* __restrict__ h, const float* __restrict__ norm,
                                             float* __restrict__ out) {
    int wv = threadIdx.x >> 6, lane = threadIdx.x & 63;
    int n = blockIdx.x * 4 + wv;
    if (n >= NN) return;
    int p0 = rowp[n], p1 = rowp[n + 1];
    float acc0 = 0.f, acc1 = 0.f, acc2 = 0.f, acc3 = 0.f;
    float den0 = 0.f, den1 = 0.f, den2 = 0.f, den3 = 0.f;
    for (int p = p0; p < p1; ++p) {
        int s = srcs[p];
        float4 w = w4[p];
        const float* zp = z + s * IND + lane;
        acc0 += w.x * zp[0];
        acc1 += w.y * zp[64];
        acc2 += w.z * zp[128];
        acc3 += w.w * zp[192];
        den0 += w.x; den1 += w.y; den2 += w.z; den3 += w.w;
    }
    float nm = norm[n];
    float r0 = (p1 > p0) ? acc0 / den0 : 0.f;
    float r1 = (p1 > p0) ? acc1 / den1 : 0.f;
    float r2 = (p1 > p0) ? acc2 / den2 : 0.f;
    float r3 = (p1 > p0) ? acc3 / den3 : 0.f;
    long b = (long)n * IND + lane;
    out[b]       = h[b]       + nm * r0;
    out[b + 64]  = h[b + 64]  + nm * r1;
    out[b + 128] = h[b + 128] + nm * r2;
    out[b + 192] = h[b + 192] + nm * r3;
}

extern "C" void kernel_launch(void* const* d_in, const int* in_sizes, int n_in,
                              void* d_out, int out_size, void* d_ws, size_t ws_size,
                              hipStream_t stream) {
    const float* h    = (const float*)d_in[0];
    const float* e    = (const float*)d_in[1];
    const float* norm = (const float*)d_in[2];
    const int*   src  = (const int*)d_in[3];
    const int*   dst  = (const int*)d_in[4];
    const float* W    = (const float*)d_in[5];
    const float* a    = (const float*)d_in[6];
    float* out = (float*)d_out;

    char* p = (char*)d_ws;
    float* Wc   = (float*)p; p += 262144;            // 256*256*4
    float* z    = (float*)p; p += 51200000;          // N*256*4
    float* ssrc = (float*)p; p += 800000;            // N*4*4
    float* sdst = (float*)p; p += 800000;
    int*   cnt  = (int*)p;   p += 200192;            // N*4 (padded)
    int*   rowp = (int*)p;   p += 200192;            // (N+1)*4 (padded)
    int*   cur  = (int*)p;   p += 200192;
    int*   srcs = (int*)p;   p += 6400000;           // E*4
    int*   dsts = (int*)p;   p += 6400000;
    float4* w4  = (float4*)p; p += 25600000;         // E*16

    hipMemsetAsync(cnt, 0, NN * sizeof(int), stream);
    k_wc<<<256, 256, 0, stream>>>(W, Wc);
    k_gemm<<<dim3(782, 4), 256, 0, stream>>>(h, norm, Wc, z);
    k_stab<<<12500, 256, 0, stream>>>(z, a, ssrc, sdst);
    k_hist<<<6250, 256, 0, stream>>>(dst, cnt);
    k_scan<<<1, 1024, 0, stream>>>(cnt, rowp, cur);
    k_scatter<<<6250, 256, 0, stream>>>(src, dst, cur, srcs, dsts);
    k_w<<<6250, 256, 0, stream>>>(srcs, dsts, (const float4*)ssrc, (const float4*)sdst, w4);
    k_agg<<<12500, 256, 0, stream>>>(z, rowp, srcs, w4, h, norm, out);
    hipMemcpyAsync(out + (size_t)NN * IND, e, NE * sizeof(float), hipMemcpyDeviceToDevice, stream);
}

// Round 9
// 574.760 us; speedup vs baseline: 1.3186x; 1.3186x over previous
//
#include <hip/hip_runtime.h>

#define NN 50000
#define NE 1600000
#define IND 256
#define OUTD 64
#define NH 4

typedef __attribute__((ext_vector_type(8))) short short8;
typedef __attribute__((ext_vector_type(4))) float f32x4;

__device__ __forceinline__ unsigned short f2bf(float x) {
    unsigned int u = __float_as_uint(x);
    u = (u + 0x7FFFu + ((u >> 16) & 1u)) >> 16;   // RNE
    return (unsigned short)u;
}

// ---- hb[n][k] = bf16(h[n][k] * norm[n]), 8 elems/thread ----
__global__ __launch_bounds__(256) void k_conv(const float* __restrict__ h, const float* __restrict__ norm,
                                              unsigned short* __restrict__ hb) {
    int t = blockIdx.x * 256 + threadIdx.x;
    if (t >= NN * IND / 8) return;
    int n = t >> 5;                                // 32 threads per 256-wide row
    float nm = norm[n];
    const float4* hp = (const float4*)h + (size_t)t * 2;
    float4 x0 = hp[0], x1 = hp[1];
    short8 r;
    r[0] = (short)f2bf(x0.x * nm); r[1] = (short)f2bf(x0.y * nm);
    r[2] = (short)f2bf(x0.z * nm); r[3] = (short)f2bf(x0.w * nm);
    r[4] = (short)f2bf(x1.x * nm); r[5] = (short)f2bf(x1.y * nm);
    r[6] = (short)f2bf(x1.z * nm); r[7] = (short)f2bf(x1.w * nm);
    *((short8*)hb + t) = r;
}

// ---- Wt[c][k] = bf16(W[c>>6][k][c&63]) : output-col-major weight, c=head*64+d ----
__global__ __launch_bounds__(256) void k_wt(const float* __restrict__ W, unsigned short* __restrict__ Wt) {
    int t = blockIdx.x * 256 + threadIdx.x;        // 65536
    int c = t >> 8, k = t & 255;
    Wt[t] = f2bf(W[(c >> 6) * IND * OUTD + k * OUTD + (c & 63)]);
}

// ---- z[N][256] = hb @ Wt^T via MFMA, LDS-free: BM=32, 4 waves = 4 c-slices of 64 ----
__global__ __launch_bounds__(256) void k_gmm(const unsigned short* __restrict__ hb,
                                             const unsigned short* __restrict__ Wt,
                                             float* __restrict__ z) {
    const int lane = threadIdx.x & 63;
    const int wv = threadIdx.x >> 6;
    const int m0 = blockIdx.x * 32;
    const int c0 = wv * 64;
    const int r16 = lane & 15, kg = lane >> 4;

    int rowA0 = m0 + r16;      if (rowA0 > NN - 1) rowA0 = NN - 1;
    int rowA1 = m0 + 16 + r16; if (rowA1 > NN - 1) rowA1 = NN - 1;
    const short8* a0p = (const short8*)(hb + (size_t)rowA0 * IND + kg * 8);
    const short8* a1p = (const short8*)(hb + (size_t)rowA1 * IND + kg * 8);
    const short8* bp0 = (const short8*)(Wt + (size_t)(c0 +  0 + r16) * IND + kg * 8);
    const short8* bp1 = (const short8*)(Wt + (size_t)(c0 + 16 + r16) * IND + kg * 8);
    const short8* bp2 = (const short8*)(Wt + (size_t)(c0 + 32 + r16) * IND + kg * 8);
    const short8* bp3 = (const short8*)(Wt + (size_t)(c0 + 48 + r16) * IND + kg * 8);

    f32x4 acc[2][4] = {};
    #pragma unroll
    for (int ks = 0; ks < 8; ++ks) {               // K-step = 32, stride in short8 = 4
        short8 a0 = a0p[ks * 4];
        short8 a1 = a1p[ks * 4];
        short8 b0 = bp0[ks * 4];
        short8 b1 = bp1[ks * 4];
        short8 b2 = bp2[ks * 4];
        short8 b3 = bp3[ks * 4];
        acc[0][0] = __builtin_amdgcn_mfma_f32_16x16x32_bf16(a0, b0, acc[0][0], 0, 0, 0);
        acc[1][0] = __builtin_amdgcn_mfma_f32_16x16x32_bf16(a1, b0, acc[1][0], 0, 0, 0);
        acc[0][1] = __builtin_amdgcn_mfma_f32_16x16x32_bf16(a0, b1, acc[0][1], 0, 0, 0);
        acc[1][1] = __builtin_amdgcn_mfma_f32_16x16x32_bf16(a1, b1, acc[1][1], 0, 0, 0);
        acc[0][2] = __builtin_amdgcn_mfma_f32_16x16x32_bf16(a0, b2, acc[0][2], 0, 0, 0);
        acc[1][2] = __builtin_amdgcn_mfma_f32_16x16x32_bf16(a1, b2, acc[1][2], 0, 0, 0);
        acc[0][3] = __builtin_amdgcn_mfma_f32_16x16x32_bf16(a0, b3, acc[0][3], 0, 0, 0);
        acc[1][3] = __builtin_amdgcn_mfma_f32_16x16x32_bf16(a1, b3, acc[1][3], 0, 0, 0);
    }
    #pragma unroll
    for (int mt = 0; mt < 2; ++mt) {
        #pragma unroll
        for (int r = 0; r < 4; ++r) {
            int row = m0 + mt * 16 + kg * 4 + r;   // D: row=(lane>>4)*4+reg, col=lane&15
            if (row < NN) {
                float* zp = z + (size_t)row * IND + c0 + r16;
                zp[0]  = acc[mt][0][r];
                zp[16] = acc[mt][1][r];
                zp[32] = acc[mt][2][r];
                zp[48] = acc[mt][3][r];
            }
        }
    }
}

// ---- per-node score halves: s_src[n][i] = z[n,i,:]·a[i,:64], s_dst = ·a[i,64:] ----
__global__ __launch_bounds__(256) void k_stab(const float* __restrict__ z, const float* __restrict__ a,
                                              float* __restrict__ ssrc, float* __restrict__ sdst) {
    int wv = threadIdx.x >> 6, lane = threadIdx.x & 63;
    int n = blockIdx.x * 4 + wv;
    if (n >= NN) return;
    #pragma unroll
    for (int i = 0; i < NH; ++i) {
        float v = z[n * IND + i * OUTD + lane];
        float ps = v * a[i * 128 + lane];
        float pd = v * a[i * 128 + 64 + lane];
        for (int off = 32; off > 0; off >>= 1) {
            ps += __shfl_down(ps, off);
            pd += __shfl_down(pd, off);
        }
        if (lane == 0) { ssrc[n * NH + i] = ps; sdst[n * NH + i] = pd; }
    }
}

// ---- CSR: histogram ----
__global__ __launch_bounds__(256) void k_hist(const int* __restrict__ dst, int* __restrict__ cnt) {
    int ed = blockIdx.x * 256 + threadIdx.x;
    if (ed < NE) atomicAdd(&cnt[dst[ed]], 1);
}

// ---- CSR: single-block exclusive scan ----
__global__ __launch_bounds__(1024) void k_scan(const int* __restrict__ cnt, int* __restrict__ rowp,
                                               int* __restrict__ cur) {
    __shared__ int wsum[16];
    __shared__ int s_carry;
    int tid = threadIdx.x, lane = tid & 63, w = tid >> 6;
    if (tid == 0) { s_carry = 0; rowp[NN] = 0; }
    __syncthreads();
    for (int base = 0; base < NN; base += 1024) {
        int i = base + tid;
        int v = (i < NN) ? cnt[i] : 0;
        int x = v;
        for (int off = 1; off < 64; off <<= 1) {
            int t = __shfl_up(x, off);
            if (lane >= off) x += t;
        }
        if (lane == 63) wsum[w] = x;
        __syncthreads();
        if (w == 0 && lane < 16) {
            int y = wsum[lane];
            for (int off = 1; off < 16; off <<= 1) {
                int t = __shfl_up(y, off, 16);
                if ((lane & 15) >= off) y += t;
            }
            wsum[lane] = y;
        }
        __syncthreads();
        int waveoff = (w == 0) ? 0 : wsum[w - 1];
        int pos = s_carry + waveoff + (x - v);
        if (i < NN) {
            rowp[i] = pos;
            cur[i] = pos;
            if (i == NN - 1) rowp[NN] = pos + v;
        }
        __syncthreads();
        if (tid == 0) s_carry += wsum[15];
        __syncthreads();
    }
}

// ---- CSR: scatter edges into dst-sorted order ----
__global__ __launch_bounds__(256) void k_scatter(const int* __restrict__ src, const int* __restrict__ dst,
                                                 int* __restrict__ cur, int* __restrict__ srcs,
                                                 int* __restrict__ dsts) {
    int ed = blockIdx.x * 256 + threadIdx.x;
    if (ed < NE) {
        int d = dst[ed];
        int p = atomicAdd(&cur[d], 1);
        srcs[p] = src[ed];
        dsts[p] = d;
    }
}

// ---- unnormalized edge weights ----
__global__ __launch_bounds__(256) void k_w(const int* __restrict__ srcs, const int* __restrict__ dsts,
                                           const float4* __restrict__ ssrc4, const float4* __restrict__ sdst4,
                                           float4* __restrict__ w4) {
    int p = blockIdx.x * 256 + threadIdx.x;
    if (p < NE) {
        float4 sa = ssrc4[srcs[p]];
        float4 sb = sdst4[dsts[p]];
        float4 r;
        r.x = __expf(sa.x + sb.x);
        r.y = __expf(sa.y + sb.y);
        r.z = __expf(sa.z + sb.z);
        r.w = __expf(sa.w + sb.w);
        w4[p] = r;
    }
}

// ---- aggregation: wave per node ----
__global__ __launch_bounds__(256) void k_agg(const float* __restrict__ z, const int* __restrict__ rowp,
                                             const int* __restrict__ srcs, const float4* __restrict__ w4,
                                             const float* __restrict__ h, const float* __restrict__ norm,
                                             float* __restrict__ out) {
    int wv = threadIdx.x >> 6, lane = threadIdx.x & 63;
    int n = blockIdx.x * 4 + wv;
    if (n >= NN) return;
    int p0 = rowp[n], p1 = rowp[n + 1];
    float acc0 = 0.f, acc1 = 0.f, acc2 = 0.f, acc3 = 0.f;
    float den0 = 0.f, den1 = 0.f, den2 = 0.f, den3 = 0.f;
    for (int p = p0; p < p1; ++p) {
        int s = srcs[p];
        float4 w = w4[p];
        const float* zp = z + (size_t)s * IND + lane;
        acc0 += w.x * zp[0];
        acc1 += w.y * zp[64];
        acc2 += w.z * zp[128];
        acc3 += w.w * zp[192];
        den0 += w.x; den1 += w.y; den2 += w.z; den3 += w.w;
    }
    float nm = norm[n];
    float r0 = (p1 > p0) ? acc0 / den0 : 0.f;
    float r1 = (p1 > p0) ? acc1 / den1 : 0.f;
    float r2 = (p1 > p0) ? acc2 / den2 : 0.f;
    float r3 = (p1 > p0) ? acc3 / den3 : 0.f;
    long b = (long)n * IND + lane;
    out[b]       = h[b]       + nm * r0;
    out[b + 64]  = h[b + 64]  + nm * r1;
    out[b + 128] = h[b + 128] + nm * r2;
    out[b + 192] = h[b + 192] + nm * r3;
}

extern "C" void kernel_launch(void* const* d_in, const int* in_sizes, int n_in,
                              void* d_out, int out_size, void* d_ws, size_t ws_size,
                              hipStream_t stream) {
    const float* h    = (const float*)d_in[0];
    const float* e    = (const float*)d_in[1];
    const float* norm = (const float*)d_in[2];
    const int*   src  = (const int*)d_in[3];
    const int*   dst  = (const int*)d_in[4];
    const float* W    = (const float*)d_in[5];
    const float* a    = (const float*)d_in[6];
    float* out = (float*)d_out;

    char* p = (char*)d_ws;
    unsigned short* Wt = (unsigned short*)p; p += 262144;   // 256*256*2 (padded slot)
    float* z    = (float*)p; p += 51200000;                 // N*256*4
    float* ssrc = (float*)p; p += 800000;
    float* sdst = (float*)p; p += 800000;
    int*   cnt  = (int*)p;   p += 200192;
    int*   rowp = (int*)p;   p += 200192;
    int*   cur  = (int*)p;   p += 200192;
    int*   srcs = (int*)p;   p += 6400000;
    int*   dsts = (int*)p;   p += 6400000;
    float4* w4  = (float4*)p; p += 25600000;                // E*16
    // hb (bf16 h*norm, 25.6 MB) aliases w4: dead before k_w writes w4
    unsigned short* hb = (unsigned short*)w4;

    hipMemsetAsync(cnt, 0, NN * sizeof(int), stream);
    k_conv<<<6250, 256, 0, stream>>>(h, norm, hb);
    k_wt<<<256, 256, 0, stream>>>(W, Wt);
    k_gmm<<<1563, 256, 0, stream>>>(hb, Wt, z);
    k_stab<<<12500, 256, 0, stream>>>(z, a, ssrc, sdst);
    k_hist<<<6250, 256, 0, stream>>>(dst, cnt);
    k_scan<<<1, 1024, 0, stream>>>(cnt, rowp, cur);
    k_scatter<<<6250, 256, 0, stream>>>(src, dst, cur, srcs, dsts);
    k_w<<<6250, 256, 0, stream>>>(srcs, dsts, (const float4*)ssrc, (const float4*)sdst, w4);
    k_agg<<<12500, 256, 0, stream>>>(z, rowp, srcs, w4, h, norm, out);
    hipMemcpyAsync(out + (size_t)NN * IND, e, NE * sizeof(float), hipMemcpyDeviceToDevice, stream);
}

// Round 10
// 484.281 us; speedup vs baseline: 1.5650x; 1.1868x over previous
//
#include <hip/hip_runtime.h>

#define NN 50000
#define NE 1600000
#define IND 256
#define OUTD 64
#define NH 4
#define NB 49   // ceil(NN/1024)

typedef __attribute__((ext_vector_type(8))) short short8;
typedef __attribute__((ext_vector_type(4))) float f32x4;

__device__ __forceinline__ unsigned short f2bf(float x) {
    unsigned int u = __float_as_uint(x);
    u = (u + 0x7FFFu + ((u >> 16) & 1u)) >> 16;   // RNE
    return (unsigned short)u;
}
__device__ __forceinline__ float bf2f(unsigned short u) {
    return __uint_as_float((unsigned int)u << 16);
}

// ---- hb[n][k] = bf16(h[n][k] * norm[n]), 8 elems/thread ----
__global__ __launch_bounds__(256) void k_conv(const float* __restrict__ h, const float* __restrict__ norm,
                                              unsigned short* __restrict__ hb) {
    int t = blockIdx.x * 256 + threadIdx.x;
    if (t >= NN * IND / 8) return;
    int n = t >> 5;
    float nm = norm[n];
    const float4* hp = (const float4*)h + (size_t)t * 2;
    float4 x0 = hp[0], x1 = hp[1];
    short8 r;
    r[0] = (short)f2bf(x0.x * nm); r[1] = (short)f2bf(x0.y * nm);
    r[2] = (short)f2bf(x0.z * nm); r[3] = (short)f2bf(x0.w * nm);
    r[4] = (short)f2bf(x1.x * nm); r[5] = (short)f2bf(x1.y * nm);
    r[6] = (short)f2bf(x1.z * nm); r[7] = (short)f2bf(x1.w * nm);
    *((short8*)hb + t) = r;
}

// ---- Wt[c][k] = bf16(W[c>>6][k][c&63]) ----
__global__ __launch_bounds__(256) void k_wt(const float* __restrict__ W, unsigned short* __restrict__ Wt) {
    int t = blockIdx.x * 256 + threadIdx.x;
    int c = t >> 8, k = t & 255;
    Wt[t] = f2bf(W[(c >> 6) * IND * OUTD + k * OUTD + (c & 63)]);
}

// ---- zb[N][256] (bf16) = hb @ Wt^T via MFMA, LDS-free ----
__global__ __launch_bounds__(256) void k_gmm(const unsigned short* __restrict__ hb,
                                             const unsigned short* __restrict__ Wt,
                                             unsigned short* __restrict__ zb) {
    const int lane = threadIdx.x & 63;
    const int wv = threadIdx.x >> 6;
    const int m0 = blockIdx.x * 32;
    const int c0 = wv * 64;
    const int r16 = lane & 15, kg = lane >> 4;

    int rowA0 = m0 + r16;      if (rowA0 > NN - 1) rowA0 = NN - 1;
    int rowA1 = m0 + 16 + r16; if (rowA1 > NN - 1) rowA1 = NN - 1;
    const short8* a0p = (const short8*)(hb + (size_t)rowA0 * IND + kg * 8);
    const short8* a1p = (const short8*)(hb + (size_t)rowA1 * IND + kg * 8);
    const short8* bp0 = (const short8*)(Wt + (size_t)(c0 +  0 + r16) * IND + kg * 8);
    const short8* bp1 = (const short8*)(Wt + (size_t)(c0 + 16 + r16) * IND + kg * 8);
    const short8* bp2 = (const short8*)(Wt + (size_t)(c0 + 32 + r16) * IND + kg * 8);
    const short8* bp3 = (const short8*)(Wt + (size_t)(c0 + 48 + r16) * IND + kg * 8);

    f32x4 acc[2][4] = {};
    #pragma unroll
    for (int ks = 0; ks < 8; ++ks) {
        short8 a0 = a0p[ks * 4];
        short8 a1 = a1p[ks * 4];
        short8 b0 = bp0[ks * 4];
        short8 b1 = bp1[ks * 4];
        short8 b2 = bp2[ks * 4];
        short8 b3 = bp3[ks * 4];
        acc[0][0] = __builtin_amdgcn_mfma_f32_16x16x32_bf16(a0, b0, acc[0][0], 0, 0, 0);
        acc[1][0] = __builtin_amdgcn_mfma_f32_16x16x32_bf16(a1, b0, acc[1][0], 0, 0, 0);
        acc[0][1] = __builtin_amdgcn_mfma_f32_16x16x32_bf16(a0, b1, acc[0][1], 0, 0, 0);
        acc[1][1] = __builtin_amdgcn_mfma_f32_16x16x32_bf16(a1, b1, acc[1][1], 0, 0, 0);
        acc[0][2] = __builtin_amdgcn_mfma_f32_16x16x32_bf16(a0, b2, acc[0][2], 0, 0, 0);
        acc[1][2] = __builtin_amdgcn_mfma_f32_16x16x32_bf16(a1, b2, acc[1][2], 0, 0, 0);
        acc[0][3] = __builtin_amdgcn_mfma_f32_16x16x32_bf16(a0, b3, acc[0][3], 0, 0, 0);
        acc[1][3] = __builtin_amdgcn_mfma_f32_16x16x32_bf16(a1, b3, acc[1][3], 0, 0, 0);
    }
    #pragma unroll
    for (int mt = 0; mt < 2; ++mt) {
        #pragma unroll
        for (int r = 0; r < 4; ++r) {
            int row = m0 + mt * 16 + kg * 4 + r;
            if (row < NN) {
                unsigned short* zp = zb + (size_t)row * IND + c0 + r16;
                zp[0]  = f2bf(acc[mt][0][r]);
                zp[16] = f2bf(acc[mt][1][r]);
                zp[32] = f2bf(acc[mt][2][r]);
                zp[48] = f2bf(acc[mt][3][r]);
            }
        }
    }
}

// ---- per-node score halves from bf16 z ----
__global__ __launch_bounds__(256) void k_stab(const unsigned short* __restrict__ zb, const float* __restrict__ a,
                                              float* __restrict__ ssrc, float* __restrict__ sdst) {
    int wv = threadIdx.x >> 6, lane = threadIdx.x & 63;
    int n = blockIdx.x * 4 + wv;
    if (n >= NN) return;
    #pragma unroll
    for (int i = 0; i < NH; ++i) {
        float v = bf2f(zb[(size_t)n * IND + i * OUTD + lane]);
        float ps = v * a[i * 128 + lane];
        float pd = v * a[i * 128 + 64 + lane];
        for (int off = 32; off > 0; off >>= 1) {
            ps += __shfl_down(ps, off);
            pd += __shfl_down(pd, off);
        }
        if (lane == 0) { ssrc[n * NH + i] = ps; sdst[n * NH + i] = pd; }
    }
}

// ---- CSR: histogram ----
__global__ __launch_bounds__(256) void k_hist(const int* __restrict__ dst, int* __restrict__ cnt) {
    int ed = blockIdx.x * 256 + threadIdx.x;
    if (ed < NE) atomicAdd(&cnt[dst[ed]], 1);
}

// ---- parallel scan step 1: per-block sums ----
__global__ __launch_bounds__(1024) void k_bsum(const int* __restrict__ cnt, int* __restrict__ bsum) {
    __shared__ int ws[16];
    int tid = threadIdx.x, lane = tid & 63, w = tid >> 6;
    int i = blockIdx.x * 1024 + tid;
    int v = (i < NN) ? cnt[i] : 0;
    for (int off = 32; off > 0; off >>= 1) v += __shfl_down(v, off);
    if (lane == 0) ws[w] = v;
    __syncthreads();
    if (tid == 0) {
        int s = 0;
        #pragma unroll
        for (int j = 0; j < 16; ++j) s += ws[j];
        bsum[blockIdx.x] = s;
    }
}

// ---- parallel scan step 2: exclusive scan of NB block sums (one wave) ----
__global__ __launch_bounds__(64) void k_bscan(const int* __restrict__ bsum, int* __restrict__ bsumx) {
    int lane = threadIdx.x;
    int v = (lane < NB) ? bsum[lane] : 0;
    int x = v;
    for (int off = 1; off < 64; off <<= 1) {
        int t = __shfl_up(x, off);
        if (lane >= off) x += t;
    }
    if (lane < NB) bsumx[lane] = x - v;
}

// ---- parallel scan step 3: per-block exclusive scan + block offset ----
__global__ __launch_bounds__(1024) void k_pscan(const int* __restrict__ cnt, const int* __restrict__ bsumx,
                                                int* __restrict__ rowp, int* __restrict__ cur) {
    __shared__ int wsum[16];
    int tid = threadIdx.x, lane = tid & 63, w = tid >> 6;
    int i = blockIdx.x * 1024 + tid;
    int v = (i < NN) ? cnt[i] : 0;
    int x = v;
    for (int off = 1; off < 64; off <<= 1) {
        int t = __shfl_up(x, off);
        if (lane >= off) x += t;
    }
    if (lane == 63) wsum[w] = x;
    __syncthreads();
    if (w == 0 && lane < 16) {
        int y = wsum[lane];
        for (int off = 1; off < 16; off <<= 1) {
            int t = __shfl_up(y, off, 16);
            if (lane >= off) y += t;
        }
        wsum[lane] = y;
    }
    __syncthreads();
    int waveoff = (w == 0) ? 0 : wsum[w - 1];
    int pos = bsumx[blockIdx.x] + waveoff + (x - v);
    if (i < NN) {
        rowp[i] = pos;
        cur[i] = pos;
        if (i == NN - 1) rowp[NN] = pos + v;
    }
}

// ---- CSR: scatter edge srcs into dst-sorted order ----
__global__ __launch_bounds__(256) void k_scatter(const int* __restrict__ src, const int* __restrict__ dst,
                                                 int* __restrict__ cur, int* __restrict__ srcs) {
    int ed = blockIdx.x * 256 + threadIdx.x;
    if (ed < NE) {
        int d = dst[ed];
        int p = atomicAdd(&cur[d], 1);
        srcs[p] = src[ed];
    }
}

// ---- aggregation: wave per node, exp fused in-loop, bf16 z gather ----
__global__ __launch_bounds__(256) void k_agg(const unsigned short* __restrict__ zb, const int* __restrict__ rowp,
                                             const int* __restrict__ srcs, const float4* __restrict__ ssrc4,
                                             const float4* __restrict__ sdst4,
                                             const float* __restrict__ h, const float* __restrict__ norm,
                                             float* __restrict__ out) {
    int wv = threadIdx.x >> 6, lane = threadIdx.x & 63;
    int n = blockIdx.x * 4 + wv;
    if (n >= NN) return;
    int p0 = rowp[n], p1 = rowp[n + 1];
    float4 sd = sdst4[n];
    float acc0 = 0.f, acc1 = 0.f, acc2 = 0.f, acc3 = 0.f;
    float den0 = 0.f, den1 = 0.f, den2 = 0.f, den3 = 0.f;
    for (int p = p0; p < p1; ++p) {
        int s = srcs[p];
        float4 sa = ssrc4[s];
        float wx = __expf(sa.x + sd.x);
        float wy = __expf(sa.y + sd.y);
        float wz = __expf(sa.z + sd.z);
        float ww = __expf(sa.w + sd.w);
        const unsigned short* zp = zb + (size_t)s * IND + lane;
        acc0 += wx * bf2f(zp[0]);
        acc1 += wy * bf2f(zp[64]);
        acc2 += wz * bf2f(zp[128]);
        acc3 += ww * bf2f(zp[192]);
        den0 += wx; den1 += wy; den2 += wz; den3 += ww;
    }
    float nm = norm[n];
    float r0 = (p1 > p0) ? acc0 / den0 : 0.f;
    float r1 = (p1 > p0) ? acc1 / den1 : 0.f;
    float r2 = (p1 > p0) ? acc2 / den2 : 0.f;
    float r3 = (p1 > p0) ? acc3 / den3 : 0.f;
    long b = (long)n * IND + lane;
    out[b]       = h[b]       + nm * r0;
    out[b + 64]  = h[b + 64]  + nm * r1;
    out[b + 128] = h[b + 128] + nm * r2;
    out[b + 192] = h[b + 192] + nm * r3;
}

extern "C" void kernel_launch(void* const* d_in, const int* in_sizes, int n_in,
                              void* d_out, int out_size, void* d_ws, size_t ws_size,
                              hipStream_t stream) {
    const float* h    = (const float*)d_in[0];
    const float* e    = (const float*)d_in[1];
    const float* norm = (const float*)d_in[2];
    const int*   src  = (const int*)d_in[3];
    const int*   dst  = (const int*)d_in[4];
    const float* W    = (const float*)d_in[5];
    const float* a    = (const float*)d_in[6];
    float* out = (float*)d_out;

    char* p = (char*)d_ws;
    unsigned short* Wt = (unsigned short*)p; p += 262144;
    unsigned short* zb = (unsigned short*)p; p += 25600000;   // N*256*2
    float* ssrc = (float*)p; p += 800000;
    float* sdst = (float*)p; p += 800000;
    int*   cnt  = (int*)p;   p += 200192;
    int*   rowp = (int*)p;   p += 200192;
    int*   cur  = (int*)p;   p += 200192;
    int*   srcs = (int*)p;   p += 6400000;
    int*   bsum = (int*)p;   p += 4096;
    int*   bsumx= (int*)p;   p += 4096;
    unsigned short* hb = (unsigned short*)p; p += 25600000;   // N*256*2

    hipMemsetAsync(cnt, 0, NN * sizeof(int), stream);
    k_conv<<<6250, 256, 0, stream>>>(h, norm, hb);
    k_wt<<<256, 256, 0, stream>>>(W, Wt);
    k_gmm<<<1563, 256, 0, stream>>>(hb, Wt, zb);
    k_stab<<<12500, 256, 0, stream>>>(zb, a, ssrc, sdst);
    k_hist<<<6250, 256, 0, stream>>>(dst, cnt);
    k_bsum<<<NB, 1024, 0, stream>>>(cnt, bsum);
    k_bscan<<<1, 64, 0, stream>>>(bsum, bsumx);
    k_pscan<<<NB, 1024, 0, stream>>>(cnt, bsumx, rowp, cur);
    k_scatter<<<6250, 256, 0, stream>>>(src, dst, cur, srcs);
    k_agg<<<12500, 256, 0, stream>>>(zb, rowp, srcs, (const float4*)ssrc, (const float4*)sdst, h, norm, out);
    hipMemcpyAsync(out + (size_t)NN * IND, e, NE * sizeof(float), hipMemcpyDeviceToDevice, stream);
}

// Round 11
// 468.333 us; speedup vs baseline: 1.6183x; 1.0341x over previous
//
#include <hip/hip_runtime.h>

#define NN 50000
#define NE 1600000
#define IND 256
#define OUTD 64
#define NH 4
#define NB 49   // ceil(NN/1024)

typedef __attribute__((ext_vector_type(8))) short short8;
typedef __attribute__((ext_vector_type(4))) float f32x4;

__device__ __forceinline__ unsigned short f2bf(float x) {
    unsigned int u = __float_as_uint(x);
    u = (u + 0x7FFFu + ((u >> 16) & 1u)) >> 16;   // RNE
    return (unsigned short)u;
}
__device__ __forceinline__ float bf2f(unsigned short u) {
    return __uint_as_float((unsigned int)u << 16);
}

// ---- hb[n][k] = bf16(h[n][k] * norm[n]), 8 elems/thread ----
__global__ __launch_bounds__(256) void k_conv(const float* __restrict__ h, const float* __restrict__ norm,
                                              unsigned short* __restrict__ hb) {
    int t = blockIdx.x * 256 + threadIdx.x;
    if (t >= NN * IND / 8) return;
    int n = t >> 5;
    float nm = norm[n];
    const float4* hp = (const float4*)h + (size_t)t * 2;
    float4 x0 = hp[0], x1 = hp[1];
    short8 r;
    r[0] = (short)f2bf(x0.x * nm); r[1] = (short)f2bf(x0.y * nm);
    r[2] = (short)f2bf(x0.z * nm); r[3] = (short)f2bf(x0.w * nm);
    r[4] = (short)f2bf(x1.x * nm); r[5] = (short)f2bf(x1.y * nm);
    r[6] = (short)f2bf(x1.z * nm); r[7] = (short)f2bf(x1.w * nm);
    *((short8*)hb + t) = r;
}

// ---- Wt[c][k] = bf16(W[c>>6][k][c&63]) ----
__global__ __launch_bounds__(256) void k_wt(const float* __restrict__ W, unsigned short* __restrict__ Wt) {
    int t = blockIdx.x * 256 + threadIdx.x;
    int c = t >> 8, k = t & 255;
    Wt[t] = f2bf(W[(c >> 6) * IND * OUTD + k * OUTD + (c & 63)]);
}

// ---- zb[N][256] (bf16) = hb @ Wt^T via MFMA, LDS-free ----
__global__ __launch_bounds__(256) void k_gmm(const unsigned short* __restrict__ hb,
                                             const unsigned short* __restrict__ Wt,
                                             unsigned short* __restrict__ zb) {
    const int lane = threadIdx.x & 63;
    const int wv = threadIdx.x >> 6;
    const int m0 = blockIdx.x * 32;
    const int c0 = wv * 64;
    const int r16 = lane & 15, kg = lane >> 4;

    int rowA0 = m0 + r16;      if (rowA0 > NN - 1) rowA0 = NN - 1;
    int rowA1 = m0 + 16 + r16; if (rowA1 > NN - 1) rowA1 = NN - 1;
    const short8* a0p = (const short8*)(hb + (size_t)rowA0 * IND + kg * 8);
    const short8* a1p = (const short8*)(hb + (size_t)rowA1 * IND + kg * 8);
    const short8* bp0 = (const short8*)(Wt + (size_t)(c0 +  0 + r16) * IND + kg * 8);
    const short8* bp1 = (const short8*)(Wt + (size_t)(c0 + 16 + r16) * IND + kg * 8);
    const short8* bp2 = (const short8*)(Wt + (size_t)(c0 + 32 + r16) * IND + kg * 8);
    const short8* bp3 = (const short8*)(Wt + (size_t)(c0 + 48 + r16) * IND + kg * 8);

    f32x4 acc[2][4] = {};
    #pragma unroll
    for (int ks = 0; ks < 8; ++ks) {
        short8 a0 = a0p[ks * 4];
        short8 a1 = a1p[ks * 4];
        short8 b0 = bp0[ks * 4];
        short8 b1 = bp1[ks * 4];
        short8 b2 = bp2[ks * 4];
        short8 b3 = bp3[ks * 4];
        acc[0][0] = __builtin_amdgcn_mfma_f32_16x16x32_bf16(a0, b0, acc[0][0], 0, 0, 0);
        acc[1][0] = __builtin_amdgcn_mfma_f32_16x16x32_bf16(a1, b0, acc[1][0], 0, 0, 0);
        acc[0][1] = __builtin_amdgcn_mfma_f32_16x16x32_bf16(a0, b1, acc[0][1], 0, 0, 0);
        acc[1][1] = __builtin_amdgcn_mfma_f32_16x16x32_bf16(a1, b1, acc[1][1], 0, 0, 0);
        acc[0][2] = __builtin_amdgcn_mfma_f32_16x16x32_bf16(a0, b2, acc[0][2], 0, 0, 0);
        acc[1][2] = __builtin_amdgcn_mfma_f32_16x16x32_bf16(a1, b2, acc[1][2], 0, 0, 0);
        acc[0][3] = __builtin_amdgcn_mfma_f32_16x16x32_bf16(a0, b3, acc[0][3], 0, 0, 0);
        acc[1][3] = __builtin_amdgcn_mfma_f32_16x16x32_bf16(a1, b3, acc[1][3], 0, 0, 0);
    }
    #pragma unroll
    for (int mt = 0; mt < 2; ++mt) {
        #pragma unroll
        for (int r = 0; r < 4; ++r) {
            int row = m0 + mt * 16 + kg * 4 + r;
            if (row < NN) {
                unsigned short* zp = zb + (size_t)row * IND + c0 + r16;
                zp[0]  = f2bf(acc[mt][0][r]);
                zp[16] = f2bf(acc[mt][1][r]);
                zp[32] = f2bf(acc[mt][2][r]);
                zp[48] = f2bf(acc[mt][3][r]);
            }
        }
    }
}

// ---- per-node score halves from bf16 z ----
__global__ __launch_bounds__(256) void k_stab(const unsigned short* __restrict__ zb, const float* __restrict__ a,
                                              float* __restrict__ ssrc, float* __restrict__ sdst) {
    int wv = threadIdx.x >> 6, lane = threadIdx.x & 63;
    int n = blockIdx.x * 4 + wv;
    if (n >= NN) return;
    #pragma unroll
    for (int i = 0; i < NH; ++i) {
        float v = bf2f(zb[(size_t)n * IND + i * OUTD + lane]);
        float ps = v * a[i * 128 + lane];
        float pd = v * a[i * 128 + 64 + lane];
        for (int off = 32; off > 0; off >>= 1) {
            ps += __shfl_down(ps, off);
            pd += __shfl_down(pd, off);
        }
        if (lane == 0) { ssrc[n * NH + i] = ps; sdst[n * NH + i] = pd; }
    }
}

// ---- CSR: histogram ----
__global__ __launch_bounds__(256) void k_hist(const int* __restrict__ dst, int* __restrict__ cnt) {
    int ed = blockIdx.x * 256 + threadIdx.x;
    if (ed < NE) atomicAdd(&cnt[dst[ed]], 1);
}

// ---- parallel scan step 1: per-block sums ----
__global__ __launch_bounds__(1024) void k_bsum(const int* __restrict__ cnt, int* __restrict__ bsum) {
    __shared__ int ws[16];
    int tid = threadIdx.x, lane = tid & 63, w = tid >> 6;
    int i = blockIdx.x * 1024 + tid;
    int v = (i < NN) ? cnt[i] : 0;
    for (int off = 32; off > 0; off >>= 1) v += __shfl_down(v, off);
    if (lane == 0) ws[w] = v;
    __syncthreads();
    if (tid == 0) {
        int s = 0;
        #pragma unroll
        for (int j = 0; j < 16; ++j) s += ws[j];
        bsum[blockIdx.x] = s;
    }
}

// ---- parallel scan step 2: exclusive scan of NB block sums (one wave) ----
__global__ __launch_bounds__(64) void k_bscan(const int* __restrict__ bsum, int* __restrict__ bsumx) {
    int lane = threadIdx.x;
    int v = (lane < NB) ? bsum[lane] : 0;
    int x = v;
    for (int off = 1; off < 64; off <<= 1) {
        int t = __shfl_up(x, off);
        if (lane >= off) x += t;
    }
    if (lane < NB) bsumx[lane] = x - v;
}

// ---- parallel scan step 3: per-block exclusive scan + block offset ----
__global__ __launch_bounds__(1024) void k_pscan(const int* __restrict__ cnt, const int* __restrict__ bsumx,
                                                int* __restrict__ rowp, int* __restrict__ cur) {
    __shared__ int wsum[16];
    int tid = threadIdx.x, lane = tid & 63, w = tid >> 6;
    int i = blockIdx.x * 1024 + tid;
    int v = (i < NN) ? cnt[i] : 0;
    int x = v;
    for (int off = 1; off < 64; off <<= 1) {
        int t = __shfl_up(x, off);
        if (lane >= off) x += t;
    }
    if (lane == 63) wsum[w] = x;
    __syncthreads();
    if (w == 0 && lane < 16) {
        int y = wsum[lane];
        for (int off = 1; off < 16; off <<= 1) {
            int t = __shfl_up(y, off, 16);
            if (lane >= off) y += t;
        }
        wsum[lane] = y;
    }
    __syncthreads();
    int waveoff = (w == 0) ? 0 : wsum[w - 1];
    int pos = bsumx[blockIdx.x] + waveoff + (x - v);
    if (i < NN) {
        rowp[i] = pos;
        cur[i] = pos;
        if (i == NN - 1) rowp[NN] = pos + v;
    }
}

// ---- CSR: scatter edge srcs into dst-sorted order ----
__global__ __launch_bounds__(256) void k_scatter(const int* __restrict__ src, const int* __restrict__ dst,
                                                 int* __restrict__ cur, int* __restrict__ srcs) {
    int ed = blockIdx.x * 256 + threadIdx.x;
    if (ed < NE) {
        int d = dst[ed];
        int p = atomicAdd(&cur[d], 1);
        srcs[p] = src[ed];
    }
}

// ---- aggregation: wave per node; lane owns 4 consecutive dims (one head) ----
__global__ __launch_bounds__(256) void k_agg(const unsigned short* __restrict__ zb, const int* __restrict__ rowp,
                                             const int* __restrict__ srcs, const float* __restrict__ ssrc,
                                             const float* __restrict__ sdst,
                                             const float* __restrict__ h, const float* __restrict__ norm,
                                             float* __restrict__ out) {
    int wv = threadIdx.x >> 6, lane = threadIdx.x & 63;
    int n = blockIdx.x * 4 + wv;
    if (n >= NN) return;
    int p0 = rowp[n], p1 = rowp[n + 1];
    int hd = lane >> 4;                       // head owning dims 4*lane..4*lane+3
    float sd = sdst[n * NH + hd];
    float a0 = 0.f, a1 = 0.f, a2 = 0.f, a3 = 0.f, den = 0.f;
    for (int p = p0; p < p1; ++p) {
        int s = srcs[p];
        float w = __expf(ssrc[s * NH + hd] + sd);
        uint2 zv = *(const uint2*)(zb + (size_t)s * IND + lane * 4);
        a0 += w * bf2f((unsigned short)(zv.x & 0xFFFFu));
        a1 += w * bf2f((unsigned short)(zv.x >> 16));
        a2 += w * bf2f((unsigned short)(zv.y & 0xFFFFu));
        a3 += w * bf2f((unsigned short)(zv.y >> 16));
        den += w;
    }
    float nm = norm[n];
    float inv = (p1 > p0) ? nm / den : 0.f;
    size_t b = (size_t)n * IND + lane * 4;
    float4 hv = *(const float4*)(h + b);
    float4 o;
    o.x = hv.x + inv * a0;
    o.y = hv.y + inv * a1;
    o.z = hv.z + inv * a2;
    o.w = hv.w + inv * a3;
    *(float4*)(out + b) = o;
}

extern "C" void kernel_launch(void* const* d_in, const int* in_sizes, int n_in,
                              void* d_out, int out_size, void* d_ws, size_t ws_size,
                              hipStream_t stream) {
    const float* h    = (const float*)d_in[0];
    const float* e    = (const float*)d_in[1];
    const float* norm = (const float*)d_in[2];
    const int*   src  = (const int*)d_in[3];
    const int*   dst  = (const int*)d_in[4];
    const float* W    = (const float*)d_in[5];
    const float* a    = (const float*)d_in[6];
    float* out = (float*)d_out;

    char* p = (char*)d_ws;
    unsigned short* Wt = (unsigned short*)p; p += 262144;
    unsigned short* zb = (unsigned short*)p; p += 25600000;   // N*256*2
    float* ssrc = (float*)p; p += 800000;
    float* sdst = (float*)p; p += 800000;
    int*   cnt  = (int*)p;   p += 200192;
    int*   rowp = (int*)p;   p += 200192;
    int*   cur  = (int*)p;   p += 200192;
    int*   srcs = (int*)p;   p += 6400000;
    int*   bsum = (int*)p;   p += 4096;
    int*   bsumx= (int*)p;   p += 4096;
    unsigned short* hb = (unsigned short*)p; p += 25600000;   // N*256*2

    hipMemsetAsync(cnt, 0, NN * sizeof(int), stream);
    k_conv<<<6250, 256, 0, stream>>>(h, norm, hb);
    k_wt<<<256, 256, 0, stream>>>(W, Wt);
    k_gmm<<<1563, 256, 0, stream>>>(hb, Wt, zb);
    k_stab<<<12500, 256, 0, stream>>>(zb, a, ssrc, sdst);
    k_hist<<<6250, 256, 0, stream>>>(dst, cnt);
    k_bsum<<<NB, 1024, 0, stream>>>(cnt, bsum);
    k_bscan<<<1, 64, 0, stream>>>(bsum, bsumx);
    k_pscan<<<NB, 1024, 0, stream>>>(cnt, bsumx, rowp, cur);
    k_scatter<<<6250, 256, 0, stream>>>(src, dst, cur, srcs);
    k_agg<<<12500, 256, 0, stream>>>(zb, rowp, srcs, ssrc, sdst, h, norm, out);
    hipMemcpyAsync(out + (size_t)NN * IND, e, NE * sizeof(float), hipMemcpyDeviceToDevice, stream);
}

// Round 12
// 434.661 us; speedup vs baseline: 1.7437x; 1.0775x over previous
//
#include <hip/hip_runtime.h>

#define NN 50000
#define NE 1600000
#define IND 256
#define OUTD 64
#define NH 4
#define NB 49   // ceil(NN/1024)

typedef __attribute__((ext_vector_type(8))) short short8;
typedef __attribute__((ext_vector_type(4))) float f32x4;

__device__ __forceinline__ unsigned short f2bf(float x) {
    unsigned int u = __float_as_uint(x);
    u = (u + 0x7FFFu + ((u >> 16) & 1u)) >> 16;   // RNE
    return (unsigned short)u;
}
__device__ __forceinline__ float bf2f(unsigned short u) {
    return __uint_as_float((unsigned int)u << 16);
}

// ---- hb[n][k] = bf16(h[n][k] * norm[n]), 8 elems/thread ----
__global__ __launch_bounds__(256) void k_conv(const float* __restrict__ h, const float* __restrict__ norm,
                                              unsigned short* __restrict__ hb) {
    int t = blockIdx.x * 256 + threadIdx.x;
    if (t >= NN * IND / 8) return;
    int n = t >> 5;
    float nm = norm[n];
    const float4* hp = (const float4*)h + (size_t)t * 2;
    float4 x0 = hp[0], x1 = hp[1];
    short8 r;
    r[0] = (short)f2bf(x0.x * nm); r[1] = (short)f2bf(x0.y * nm);
    r[2] = (short)f2bf(x0.z * nm); r[3] = (short)f2bf(x0.w * nm);
    r[4] = (short)f2bf(x1.x * nm); r[5] = (short)f2bf(x1.y * nm);
    r[6] = (short)f2bf(x1.z * nm); r[7] = (short)f2bf(x1.w * nm);
    *((short8*)hb + t) = r;
}

// ---- Wt[c][k] = bf16(W[c>>6][k][c&63]) ----
__global__ __launch_bounds__(256) void k_wt(const float* __restrict__ W, unsigned short* __restrict__ Wt) {
    int t = blockIdx.x * 256 + threadIdx.x;
    int c = t >> 8, k = t & 255;
    Wt[t] = f2bf(W[(c >> 6) * IND * OUTD + k * OUTD + (c & 63)]);
}

// ---- zb[N][256] (bf16) = hb @ Wt^T via MFMA, LDS-free ----
__global__ __launch_bounds__(256) void k_gmm(const unsigned short* __restrict__ hb,
                                             const unsigned short* __restrict__ Wt,
                                             unsigned short* __restrict__ zb) {
    const int lane = threadIdx.x & 63;
    const int wv = threadIdx.x >> 6;
    const int m0 = blockIdx.x * 32;
    const int c0 = wv * 64;
    const int r16 = lane & 15, kg = lane >> 4;

    int rowA0 = m0 + r16;      if (rowA0 > NN - 1) rowA0 = NN - 1;
    int rowA1 = m0 + 16 + r16; if (rowA1 > NN - 1) rowA1 = NN - 1;
    const short8* a0p = (const short8*)(hb + (size_t)rowA0 * IND + kg * 8);
    const short8* a1p = (const short8*)(hb + (size_t)rowA1 * IND + kg * 8);
    const short8* bp0 = (const short8*)(Wt + (size_t)(c0 +  0 + r16) * IND + kg * 8);
    const short8* bp1 = (const short8*)(Wt + (size_t)(c0 + 16 + r16) * IND + kg * 8);
    const short8* bp2 = (const short8*)(Wt + (size_t)(c0 + 32 + r16) * IND + kg * 8);
    const short8* bp3 = (const short8*)(Wt + (size_t)(c0 + 48 + r16) * IND + kg * 8);

    f32x4 acc[2][4] = {};
    #pragma unroll
    for (int ks = 0; ks < 8; ++ks) {
        short8 a0 = a0p[ks * 4];
        short8 a1 = a1p[ks * 4];
        short8 b0 = bp0[ks * 4];
        short8 b1 = bp1[ks * 4];
        short8 b2 = bp2[ks * 4];
        short8 b3 = bp3[ks * 4];
        acc[0][0] = __builtin_amdgcn_mfma_f32_16x16x32_bf16(a0, b0, acc[0][0], 0, 0, 0);
        acc[1][0] = __builtin_amdgcn_mfma_f32_16x16x32_bf16(a1, b0, acc[1][0], 0, 0, 0);
        acc[0][1] = __builtin_amdgcn_mfma_f32_16x16x32_bf16(a0, b1, acc[0][1], 0, 0, 0);
        acc[1][1] = __builtin_amdgcn_mfma_f32_16x16x32_bf16(a1, b1, acc[1][1], 0, 0, 0);
        acc[0][2] = __builtin_amdgcn_mfma_f32_16x16x32_bf16(a0, b2, acc[0][2], 0, 0, 0);
        acc[1][2] = __builtin_amdgcn_mfma_f32_16x16x32_bf16(a1, b2, acc[1][2], 0, 0, 0);
        acc[0][3] = __builtin_amdgcn_mfma_f32_16x16x32_bf16(a0, b3, acc[0][3], 0, 0, 0);
        acc[1][3] = __builtin_amdgcn_mfma_f32_16x16x32_bf16(a1, b3, acc[1][3], 0, 0, 0);
    }
    #pragma unroll
    for (int mt = 0; mt < 2; ++mt) {
        #pragma unroll
        for (int r = 0; r < 4; ++r) {
            int row = m0 + mt * 16 + kg * 4 + r;
            if (row < NN) {
                unsigned short* zp = zb + (size_t)row * IND + c0 + r16;
                zp[0]  = f2bf(acc[mt][0][r]);
                zp[16] = f2bf(acc[mt][1][r]);
                zp[32] = f2bf(acc[mt][2][r]);
                zp[48] = f2bf(acc[mt][3][r]);
            }
        }
    }
}

// ---- per-node score halves from bf16 z ----
__global__ __launch_bounds__(256) void k_stab(const unsigned short* __restrict__ zb, const float* __restrict__ a,
                                              float* __restrict__ ssrc, float* __restrict__ sdst) {
    int wv = threadIdx.x >> 6, lane = threadIdx.x & 63;
    int n = blockIdx.x * 4 + wv;
    if (n >= NN) return;
    #pragma unroll
    for (int i = 0; i < NH; ++i) {
        float v = bf2f(zb[(size_t)n * IND + i * OUTD + lane]);
        float ps = v * a[i * 128 + lane];
        float pd = v * a[i * 128 + 64 + lane];
        for (int off = 32; off > 0; off >>= 1) {
            ps += __shfl_down(ps, off);
            pd += __shfl_down(pd, off);
        }
        if (lane == 0) { ssrc[n * NH + i] = ps; sdst[n * NH + i] = pd; }
    }
}

// ---- CSR: histogram ----
__global__ __launch_bounds__(256) void k_hist(const int* __restrict__ dst, int* __restrict__ cnt) {
    int ed = blockIdx.x * 256 + threadIdx.x;
    if (ed < NE) atomicAdd(&cnt[dst[ed]], 1);
}

// ---- parallel scan step 1: per-block sums ----
__global__ __launch_bounds__(1024) void k_bsum(const int* __restrict__ cnt, int* __restrict__ bsum) {
    __shared__ int ws[16];
    int tid = threadIdx.x, lane = tid & 63, w = tid >> 6;
    int i = blockIdx.x * 1024 + tid;
    int v = (i < NN) ? cnt[i] : 0;
    for (int off = 32; off > 0; off >>= 1) v += __shfl_down(v, off);
    if (lane == 0) ws[w] = v;
    __syncthreads();
    if (tid == 0) {
        int s = 0;
        #pragma unroll
        for (int j = 0; j < 16; ++j) s += ws[j];
        bsum[blockIdx.x] = s;
    }
}

// ---- parallel scan step 2: exclusive scan of NB block sums (one wave) ----
__global__ __launch_bounds__(64) void k_bscan(const int* __restrict__ bsum, int* __restrict__ bsumx) {
    int lane = threadIdx.x;
    int v = (lane < NB) ? bsum[lane] : 0;
    int x = v;
    for (int off = 1; off < 64; off <<= 1) {
        int t = __shfl_up(x, off);
        if (lane >= off) x += t;
    }
    if (lane < NB) bsumx[lane] = x - v;
}

// ---- parallel scan step 3: per-block exclusive scan + block offset ----
__global__ __launch_bounds__(1024) void k_pscan(const int* __restrict__ cnt, const int* __restrict__ bsumx,
                                                int* __restrict__ rowp, int* __restrict__ cur) {
    __shared__ int wsum[16];
    int tid = threadIdx.x, lane = tid & 63, w = tid >> 6;
    int i = blockIdx.x * 1024 + tid;
    int v = (i < NN) ? cnt[i] : 0;
    int x = v;
    for (int off = 1; off < 64; off <<= 1) {
        int t = __shfl_up(x, off);
        if (lane >= off) x += t;
    }
    if (lane == 63) wsum[w] = x;
    __syncthreads();
    if (w == 0 && lane < 16) {
        int y = wsum[lane];
        for (int off = 1; off < 16; off <<= 1) {
            int t = __shfl_up(y, off, 16);
            if (lane >= off) y += t;
        }
        wsum[lane] = y;
    }
    __syncthreads();
    int waveoff = (w == 0) ? 0 : wsum[w - 1];
    int pos = bsumx[blockIdx.x] + waveoff + (x - v);
    if (i < NN) {
        rowp[i] = pos;
        cur[i] = pos;
        if (i == NN - 1) rowp[NN] = pos + v;
    }
}

// ---- CSR: scatter edge srcs into dst-sorted order ----
__global__ __launch_bounds__(256) void k_scatter(const int* __restrict__ src, const int* __restrict__ dst,
                                                 int* __restrict__ cur, int* __restrict__ srcs) {
    int ed = blockIdx.x * 256 + threadIdx.x;
    if (ed < NE) {
        int d = dst[ed];
        int p = atomicAdd(&cur[d], 1);
        srcs[p] = src[ed];
    }
}

// ---- aggregation: half-wave per node; lane owns 8 consecutive dims (uint4/16B) ----
__global__ __launch_bounds__(256) void k_agg(const unsigned short* __restrict__ zb, const int* __restrict__ rowp,
                                             const int* __restrict__ srcs, const float* __restrict__ ssrc,
                                             const float* __restrict__ sdst,
                                             const float* __restrict__ h, const float* __restrict__ norm,
                                             float* __restrict__ out) {
    int wv = threadIdx.x >> 6, lane = threadIdx.x & 63;
    int half = lane >> 5;                     // which node of the pair
    int l = lane & 31;                        // lane within half-wave
    int n = blockIdx.x * 8 + wv * 2 + half;   // 8 nodes per block, exact cover of 50000
    if (n >= NN) return;
    int p0 = rowp[n], p1 = rowp[n + 1];
    int deg = p1 - p0;
    int hd = l >> 3;                          // head owning dims 8l..8l+7
    float sd = sdst[(n << 2) + hd];
    float a0 = 0.f, a1 = 0.f, a2 = 0.f, a3 = 0.f;
    float a4 = 0.f, a5 = 0.f, a6 = 0.f, a7 = 0.f;
    float den = 0.f;
    int zoffl = l << 3;                       // element offset of this lane's 8 dims
    for (int i = 0; i < deg; ++i) {
        int s = srcs[p0 + i];
        float w = __expf(ssrc[(s << 2) + hd] + sd);
        uint4 zv = *(const uint4*)(zb + (s << 8) + zoffl);
        a0 += w * bf2f((unsigned short)(zv.x & 0xFFFFu));
        a1 += w * bf2f((unsigned short)(zv.x >> 16));
        a2 += w * bf2f((unsigned short)(zv.y & 0xFFFFu));
        a3 += w * bf2f((unsigned short)(zv.y >> 16));
        a4 += w * bf2f((unsigned short)(zv.z & 0xFFFFu));
        a5 += w * bf2f((unsigned short)(zv.z >> 16));
        a6 += w * bf2f((unsigned short)(zv.w & 0xFFFFu));
        a7 += w * bf2f((unsigned short)(zv.w >> 16));
        den += w;
    }
    float nm = norm[n];
    float inv = (deg > 0) ? nm / den : 0.f;
    size_t b = (size_t)n * IND + zoffl;
    float4 h0 = *(const float4*)(h + b);
    float4 h1 = *(const float4*)(h + b + 4);
    float4 o0, o1;
    o0.x = h0.x + inv * a0; o0.y = h0.y + inv * a1;
    o0.z = h0.z + inv * a2; o0.w = h0.w + inv * a3;
    o1.x = h1.x + inv * a4; o1.y = h1.y + inv * a5;
    o1.z = h1.z + inv * a6; o1.w = h1.w + inv * a7;
    *(float4*)(out + b) = o0;
    *(float4*)(out + b + 4) = o1;
}

extern "C" void kernel_launch(void* const* d_in, const int* in_sizes, int n_in,
                              void* d_out, int out_size, void* d_ws, size_t ws_size,
                              hipStream_t stream) {
    const float* h    = (const float*)d_in[0];
    const float* e    = (const float*)d_in[1];
    const float* norm = (const float*)d_in[2];
    const int*   src  = (const int*)d_in[3];
    const int*   dst  = (const int*)d_in[4];
    const float* W    = (const float*)d_in[5];
    const float* a    = (const float*)d_in[6];
    float* out = (float*)d_out;

    char* p = (char*)d_ws;
    unsigned short* Wt = (unsigned short*)p; p += 262144;
    unsigned short* zb = (unsigned short*)p; p += 25600000;   // N*256*2
    float* ssrc = (float*)p; p += 800000;
    float* sdst = (float*)p; p += 800000;
    int*   cnt  = (int*)p;   p += 200192;
    int*   rowp = (int*)p;   p += 200192;
    int*   cur  = (int*)p;   p += 200192;
    int*   srcs = (int*)p;   p += 6400000;
    int*   bsum = (int*)p;   p += 4096;
    int*   bsumx= (int*)p;   p += 4096;
    unsigned short* hb = (unsigned short*)p; p += 25600000;   // N*256*2

    hipMemsetAsync(cnt, 0, NN * sizeof(int), stream);
    k_conv<<<6250, 256, 0, stream>>>(h, norm, hb);
    k_wt<<<256, 256, 0, stream>>>(W, Wt);
    k_gmm<<<1563, 256, 0, stream>>>(hb, Wt, zb);
    k_stab<<<12500, 256, 0, stream>>>(zb, a, ssrc, sdst);
    k_hist<<<6250, 256, 0, stream>>>(dst, cnt);
    k_bsum<<<NB, 1024, 0, stream>>>(cnt, bsum);
    k_bscan<<<1, 64, 0, stream>>>(bsum, bsumx);
    k_pscan<<<NB, 1024, 0, stream>>>(cnt, bsumx, rowp, cur);
    k_scatter<<<6250, 256, 0, stream>>>(src, dst, cur, srcs);
    k_agg<<<6250, 256, 0, stream>>>(zb, rowp, srcs, ssrc, sdst, h, norm, out);
    hipMemcpyAsync(out + (size_t)NN * IND, e, NE * sizeof(float), hipMemcpyDeviceToDevice, stream);
}

// Round 13
// 400.044 us; speedup vs baseline: 1.8946x; 1.0865x over previous
//
#include <hip/hip_runtime.h>

#define NN 50000
#define NE 1600000
#define IND 256
#define OUTD 64
#define NH 4
#define NB 49   // ceil(NN/1024)

typedef __attribute__((ext_vector_type(8))) short short8;
typedef __attribute__((ext_vector_type(4))) float f32x4;

__device__ __forceinline__ unsigned short f2bf(float x) {
    unsigned int u = __float_as_uint(x);
    u = (u + 0x7FFFu + ((u >> 16) & 1u)) >> 16;   // RNE
    return (unsigned short)u;
}
__device__ __forceinline__ float bf2f(unsigned short u) {
    return __uint_as_float((unsigned int)u << 16);
}

// ---- Wt[c][k] = bf16(W[c>>6][k][c&63]) ----
__global__ __launch_bounds__(256) void k_wt(const float* __restrict__ W, unsigned short* __restrict__ Wt) {
    int t = blockIdx.x * 256 + threadIdx.x;
    int c = t >> 8, k = t & 255;
    Wt[t] = f2bf(W[(c >> 6) * IND * OUTD + k * OUTD + (c & 63)]);
}

// ---- fused: zb = bf16((h*norm) @ Wt^T) via MFMA + inline conv + s_src/s_dst epilogue ----
// wave wv owns head wv (cols c0..c0+63) for rows m0..m0+31
__global__ __launch_bounds__(256) void k_gmm(const float* __restrict__ h, const float* __restrict__ norm,
                                             const unsigned short* __restrict__ Wt, const float* __restrict__ a,
                                             unsigned short* __restrict__ zb,
                                             float* __restrict__ ssrc, float* __restrict__ sdst) {
    const int lane = threadIdx.x & 63;
    const int wv = threadIdx.x >> 6;          // head index
    const int m0 = blockIdx.x * 32;
    const int c0 = wv * 64;
    const int r16 = lane & 15, kg = lane >> 4;

    int rowA0 = m0 + r16;      if (rowA0 > NN - 1) rowA0 = NN - 1;
    int rowA1 = m0 + 16 + r16; if (rowA1 > NN - 1) rowA1 = NN - 1;
    float nm0 = norm[rowA0], nm1 = norm[rowA1];
    const float4* h0p = (const float4*)(h + (size_t)rowA0 * IND + kg * 8);
    const float4* h1p = (const float4*)(h + (size_t)rowA1 * IND + kg * 8);
    const short8* bp0 = (const short8*)(Wt + (size_t)(c0 +  0 + r16) * IND + kg * 8);
    const short8* bp1 = (const short8*)(Wt + (size_t)(c0 + 16 + r16) * IND + kg * 8);
    const short8* bp2 = (const short8*)(Wt + (size_t)(c0 + 32 + r16) * IND + kg * 8);
    const short8* bp3 = (const short8*)(Wt + (size_t)(c0 + 48 + r16) * IND + kg * 8);

    f32x4 acc[2][4] = {};
    #pragma unroll
    for (int ks = 0; ks < 8; ++ks) {          // K-step 32: float4 stride 8, short8 stride 4
        float4 x00 = h0p[ks * 8], x01 = h0p[ks * 8 + 1];
        float4 x10 = h1p[ks * 8], x11 = h1p[ks * 8 + 1];
        short8 a0, a1;
        a0[0] = (short)f2bf(x00.x * nm0); a0[1] = (short)f2bf(x00.y * nm0);
        a0[2] = (short)f2bf(x00.z * nm0); a0[3] = (short)f2bf(x00.w * nm0);
        a0[4] = (short)f2bf(x01.x * nm0); a0[5] = (short)f2bf(x01.y * nm0);
        a0[6] = (short)f2bf(x01.z * nm0); a0[7] = (short)f2bf(x01.w * nm0);
        a1[0] = (short)f2bf(x10.x * nm1); a1[1] = (short)f2bf(x10.y * nm1);
        a1[2] = (short)f2bf(x10.z * nm1); a1[3] = (short)f2bf(x10.w * nm1);
        a1[4] = (short)f2bf(x11.x * nm1); a1[5] = (short)f2bf(x11.y * nm1);
        a1[6] = (short)f2bf(x11.z * nm1); a1[7] = (short)f2bf(x11.w * nm1);
        short8 b0 = bp0[ks * 4];
        short8 b1 = bp1[ks * 4];
        short8 b2 = bp2[ks * 4];
        short8 b3 = bp3[ks * 4];
        acc[0][0] = __builtin_amdgcn_mfma_f32_16x16x32_bf16(a0, b0, acc[0][0], 0, 0, 0);
        acc[1][0] = __builtin_amdgcn_mfma_f32_16x16x32_bf16(a1, b0, acc[1][0], 0, 0, 0);
        acc[0][1] = __builtin_amdgcn_mfma_f32_16x16x32_bf16(a0, b1, acc[0][1], 0, 0, 0);
        acc[1][1] = __builtin_amdgcn_mfma_f32_16x16x32_bf16(a1, b1, acc[1][1], 0, 0, 0);
        acc[0][2] = __builtin_amdgcn_mfma_f32_16x16x32_bf16(a0, b2, acc[0][2], 0, 0, 0);
        acc[1][2] = __builtin_amdgcn_mfma_f32_16x16x32_bf16(a1, b2, acc[1][2], 0, 0, 0);
        acc[0][3] = __builtin_amdgcn_mfma_f32_16x16x32_bf16(a0, b3, acc[0][3], 0, 0, 0);
        acc[1][3] = __builtin_amdgcn_mfma_f32_16x16x32_bf16(a1, b3, acc[1][3], 0, 0, 0);
    }

    // a-vector slices for this head: d = j*16 + r16
    float asrc[4], adst[4];
    #pragma unroll
    for (int j = 0; j < 4; ++j) {
        asrc[j] = a[wv * 128 + j * 16 + r16];
        adst[j] = a[wv * 128 + 64 + j * 16 + r16];
    }
    #pragma unroll
    for (int mt = 0; mt < 2; ++mt) {
        #pragma unroll
        for (int r = 0; r < 4; ++r) {
            int row = m0 + mt * 16 + kg * 4 + r;     // D: row=(lane>>4)*4+reg, col=lane&15
            unsigned short q0 = f2bf(acc[mt][0][r]);
            unsigned short q1 = f2bf(acc[mt][1][r]);
            unsigned short q2 = f2bf(acc[mt][2][r]);
            unsigned short q3 = f2bf(acc[mt][3][r]);
            float ps = bf2f(q0) * asrc[0] + bf2f(q1) * asrc[1] + bf2f(q2) * asrc[2] + bf2f(q3) * asrc[3];
            float pd = bf2f(q0) * adst[0] + bf2f(q1) * adst[1] + bf2f(q2) * adst[2] + bf2f(q3) * adst[3];
            #pragma unroll
            for (int off = 1; off < 16; off <<= 1) { // reduce over the 16-lane col group
                ps += __shfl_xor(ps, off);
                pd += __shfl_xor(pd, off);
            }
            if (row < NN) {
                unsigned short* zp = zb + (size_t)row * IND + c0 + r16;
                zp[0]  = q0;
                zp[16] = q1;
                zp[32] = q2;
                zp[48] = q3;
                if (r16 == 0) {
                    ssrc[(row << 2) + wv] = ps;
                    sdst[(row << 2) + wv] = pd;
                }
            }
        }
    }
}

// ---- CSR: histogram ----
__global__ __launch_bounds__(256) void k_hist(const int* __restrict__ dst, int* __restrict__ cnt) {
    int ed = blockIdx.x * 256 + threadIdx.x;
    if (ed < NE) atomicAdd(&cnt[dst[ed]], 1);
}

// ---- parallel scan step 1: per-block sums ----
__global__ __launch_bounds__(1024) void k_bsum(const int* __restrict__ cnt, int* __restrict__ bsum) {
    __shared__ int ws[16];
    int tid = threadIdx.x, lane = tid & 63, w = tid >> 6;
    int i = blockIdx.x * 1024 + tid;
    int v = (i < NN) ? cnt[i] : 0;
    for (int off = 32; off > 0; off >>= 1) v += __shfl_down(v, off);
    if (lane == 0) ws[w] = v;
    __syncthreads();
    if (tid == 0) {
        int s = 0;
        #pragma unroll
        for (int j = 0; j < 16; ++j) s += ws[j];
        bsum[blockIdx.x] = s;
    }
}

// ---- parallel scan step 2: exclusive scan of NB block sums ----
__global__ __launch_bounds__(64) void k_bscan(const int* __restrict__ bsum, int* __restrict__ bsumx) {
    int lane = threadIdx.x;
    int v = (lane < NB) ? bsum[lane] : 0;
    int x = v;
    for (int off = 1; off < 64; off <<= 1) {
        int t = __shfl_up(x, off);
        if (lane >= off) x += t;
    }
    if (lane < NB) bsumx[lane] = x - v;
}

// ---- parallel scan step 3: per-block exclusive scan + block offset ----
__global__ __launch_bounds__(1024) void k_pscan(const int* __restrict__ cnt, const int* __restrict__ bsumx,
                                                int* __restrict__ rowp, int* __restrict__ cur) {
    __shared__ int wsum[16];
    int tid = threadIdx.x, lane = tid & 63, w = tid >> 6;
    int i = blockIdx.x * 1024 + tid;
    int v = (i < NN) ? cnt[i] : 0;
    int x = v;
    for (int off = 1; off < 64; off <<= 1) {
        int t = __shfl_up(x, off);
        if (lane >= off) x += t;
    }
    if (lane == 63) wsum[w] = x;
    __syncthreads();
    if (w == 0 && lane < 16) {
        int y = wsum[lane];
        for (int off = 1; off < 16; off <<= 1) {
            int t = __shfl_up(y, off, 16);
            if (lane >= off) y += t;
        }
        wsum[lane] = y;
    }
    __syncthreads();
    int waveoff = (w == 0) ? 0 : wsum[w - 1];
    int pos = bsumx[blockIdx.x] + waveoff + (x - v);
    if (i < NN) {
        rowp[i] = pos;
        cur[i] = pos;
        if (i == NN - 1) rowp[NN] = pos + v;
    }
}

// ---- CSR: scatter edge srcs into dst-sorted order ----
__global__ __launch_bounds__(256) void k_scatter(const int* __restrict__ src, const int* __restrict__ dst,
                                                 int* __restrict__ cur, int* __restrict__ srcs) {
    int ed = blockIdx.x * 256 + threadIdx.x;
    if (ed < NE) {
        int d = dst[ed];
        int p = atomicAdd(&cur[d], 1);
        srcs[p] = src[ed];
    }
}

// ---- aggregation: half-wave per node; lane owns 8 dims; 2-way edge unroll ----
__global__ __launch_bounds__(256) void k_agg(const unsigned short* __restrict__ zb, const int* __restrict__ rowp,
                                             const int* __restrict__ srcs, const float* __restrict__ ssrc,
                                             const float* __restrict__ sdst,
                                             const float* __restrict__ h, const float* __restrict__ norm,
                                             float* __restrict__ out) {
    int wv = threadIdx.x >> 6, lane = threadIdx.x & 63;
    int half = lane >> 5;
    int l = lane & 31;
    int n = blockIdx.x * 8 + wv * 2 + half;
    if (n >= NN) return;
    int p0 = rowp[n], p1 = rowp[n + 1];
    int deg = p1 - p0;
    int hd = l >> 3;
    float sd = sdst[(n << 2) + hd];
    float a0 = 0.f, a1 = 0.f, a2 = 0.f, a3 = 0.f;
    float a4 = 0.f, a5 = 0.f, a6 = 0.f, a7 = 0.f;
    float b0 = 0.f, b1 = 0.f, b2 = 0.f, b3 = 0.f;
    float b4 = 0.f, b5 = 0.f, b6 = 0.f, b7 = 0.f;
    float denA = 0.f, denB = 0.f;
    int zoffl = l << 3;
    int i = 0;
    for (; i + 2 <= deg; i += 2) {
        int s0 = srcs[p0 + i];
        int s1 = srcs[p0 + i + 1];
        float w0 = __expf(ssrc[(s0 << 2) + hd] + sd);
        float w1 = __expf(ssrc[(s1 << 2) + hd] + sd);
        uint4 z0 = *(const uint4*)(zb + (s0 << 8) + zoffl);
        uint4 z1 = *(const uint4*)(zb + (s1 << 8) + zoffl);
        a0 += w0 * bf2f((unsigned short)(z0.x & 0xFFFFu));
        a1 += w0 * bf2f((unsigned short)(z0.x >> 16));
        a2 += w0 * bf2f((unsigned short)(z0.y & 0xFFFFu));
        a3 += w0 * bf2f((unsigned short)(z0.y >> 16));
        a4 += w0 * bf2f((unsigned short)(z0.z & 0xFFFFu));
        a5 += w0 * bf2f((unsigned short)(z0.z >> 16));
        a6 += w0 * bf2f((unsigned short)(z0.w & 0xFFFFu));
        a7 += w0 * bf2f((unsigned short)(z0.w >> 16));
        denA += w0;
        b0 += w1 * bf2f((unsigned short)(z1.x & 0xFFFFu));
        b1 += w1 * bf2f((unsigned short)(z1.x >> 16));
        b2 += w1 * bf2f((unsigned short)(z1.y & 0xFFFFu));
        b3 += w1 * bf2f((unsigned short)(z1.y >> 16));
        b4 += w1 * bf2f((unsigned short)(z1.z & 0xFFFFu));
        b5 += w1 * bf2f((unsigned short)(z1.z >> 16));
        b6 += w1 * bf2f((unsigned short)(z1.w & 0xFFFFu));
        b7 += w1 * bf2f((unsigned short)(z1.w >> 16));
        denB += w1;
    }
    if (i < deg) {
        int s0 = srcs[p0 + i];
        float w0 = __expf(ssrc[(s0 << 2) + hd] + sd);
        uint4 z0 = *(const uint4*)(zb + (s0 << 8) + zoffl);
        a0 += w0 * bf2f((unsigned short)(z0.x & 0xFFFFu));
        a1 += w0 * bf2f((unsigned short)(z0.x >> 16));
        a2 += w0 * bf2f((unsigned short)(z0.y & 0xFFFFu));
        a3 += w0 * bf2f((unsigned short)(z0.y >> 16));
        a4 += w0 * bf2f((unsigned short)(z0.z & 0xFFFFu));
        a5 += w0 * bf2f((unsigned short)(z0.z >> 16));
        a6 += w0 * bf2f((unsigned short)(z0.w & 0xFFFFu));
        a7 += w0 * bf2f((unsigned short)(z0.w >> 16));
        denA += w0;
    }
    a0 += b0; a1 += b1; a2 += b2; a3 += b3;
    a4 += b4; a5 += b5; a6 += b6; a7 += b7;
    float den = denA + denB;
    float nm = norm[n];
    float inv = (deg > 0) ? nm / den : 0.f;
    size_t b = (size_t)n * IND + zoffl;
    float4 h0 = *(const float4*)(h + b);
    float4 h1 = *(const float4*)(h + b + 4);
    float4 o0, o1;
    o0.x = h0.x + inv * a0; o0.y = h0.y + inv * a1;
    o0.z = h0.z + inv * a2; o0.w = h0.w + inv * a3;
    o1.x = h1.x + inv * a4; o1.y = h1.y + inv * a5;
    o1.z = h1.z + inv * a6; o1.w = h1.w + inv * a7;
    *(float4*)(out + b) = o0;
    *(float4*)(out + b + 4) = o1;
}

extern "C" void kernel_launch(void* const* d_in, const int* in_sizes, int n_in,
                              void* d_out, int out_size, void* d_ws, size_t ws_size,
                              hipStream_t stream) {
    const float* h    = (const float*)d_in[0];
    const float* e    = (const float*)d_in[1];
    const float* norm = (const float*)d_in[2];
    const int*   src  = (const int*)d_in[3];
    const int*   dst  = (const int*)d_in[4];
    const float* W    = (const float*)d_in[5];
    const float* a    = (const float*)d_in[6];
    float* out = (float*)d_out;

    char* p = (char*)d_ws;
    unsigned short* Wt = (unsigned short*)p; p += 262144;
    unsigned short* zb = (unsigned short*)p; p += 25600000;   // N*256*2
    float* ssrc = (float*)p; p += 800000;
    float* sdst = (float*)p; p += 800000;
    int*   cnt  = (int*)p;   p += 200192;
    int*   rowp = (int*)p;   p += 200192;
    int*   cur  = (int*)p;   p += 200192;
    int*   srcs = (int*)p;   p += 6400000;
    int*   bsum = (int*)p;   p += 4096;
    int*   bsumx= (int*)p;   p += 4096;

    hipMemsetAsync(cnt, 0, NN * sizeof(int), stream);
    k_wt<<<256, 256, 0, stream>>>(W, Wt);
    k_gmm<<<1563, 256, 0, stream>>>(h, norm, Wt, a, zb, ssrc, sdst);
    k_hist<<<6250, 256, 0, stream>>>(dst, cnt);
    k_bsum<<<NB, 1024, 0, stream>>>(cnt, bsum);
    k_bscan<<<1, 64, 0, stream>>>(bsum, bsumx);
    k_pscan<<<NB, 1024, 0, stream>>>(cnt, bsumx, rowp, cur);
    k_scatter<<<6250, 256, 0, stream>>>(src, dst, cur, srcs);
    k_agg<<<6250, 256, 0, stream>>>(zb, rowp, srcs, ssrc, sdst, h, norm, out);
    hipMemcpyAsync(out + (size_t)NN * IND, e, NE * sizeof(float), hipMemcpyDeviceToDevice, stream);
}

// Round 14
// 390.553 us; speedup vs baseline: 1.9406x; 1.0243x over previous
//
#include <hip/hip_runtime.h>

#define NN 50000
#define NE 1600000
#define IND 256
#define OUTD 64
#define NH 4
#define NB 49   // ceil(NN/1024)

typedef __attribute__((ext_vector_type(8))) short short8;
typedef __attribute__((ext_vector_type(4))) float f32x4;

__device__ __forceinline__ unsigned short f2bf(float x) {
    unsigned int u = __float_as_uint(x);
    u = (u + 0x7FFFu + ((u >> 16) & 1u)) >> 16;   // RNE
    return (unsigned short)u;
}
__device__ __forceinline__ float bf2f(unsigned short u) {
    return __uint_as_float((unsigned int)u << 16);
}

// ---- Wt[c][k] = bf16(W[c>>6][k][c&63]) ----
__global__ __launch_bounds__(256) void k_wt(const float* __restrict__ W, unsigned short* __restrict__ Wt) {
    int t = blockIdx.x * 256 + threadIdx.x;
    int c = t >> 8, k = t & 255;
    Wt[t] = f2bf(W[(c >> 6) * IND * OUTD + k * OUTD + (c & 63)]);
}

// ---- fused: zb = bf16((h*norm) @ Wt^T) via MFMA + inline conv + s_src/s_dst epilogue ----
__global__ __launch_bounds__(256) void k_gmm(const float* __restrict__ h, const float* __restrict__ norm,
                                             const unsigned short* __restrict__ Wt, const float* __restrict__ a,
                                             unsigned short* __restrict__ zb,
                                             float* __restrict__ ssrc, float* __restrict__ sdst) {
    const int lane = threadIdx.x & 63;
    const int wv = threadIdx.x >> 6;          // head index
    const int m0 = blockIdx.x * 32;
    const int c0 = wv * 64;
    const int r16 = lane & 15, kg = lane >> 4;

    int rowA0 = m0 + r16;      if (rowA0 > NN - 1) rowA0 = NN - 1;
    int rowA1 = m0 + 16 + r16; if (rowA1 > NN - 1) rowA1 = NN - 1;
    float nm0 = norm[rowA0], nm1 = norm[rowA1];
    const float4* h0p = (const float4*)(h + (size_t)rowA0 * IND + kg * 8);
    const float4* h1p = (const float4*)(h + (size_t)rowA1 * IND + kg * 8);
    const short8* bp0 = (const short8*)(Wt + (size_t)(c0 +  0 + r16) * IND + kg * 8);
    const short8* bp1 = (const short8*)(Wt + (size_t)(c0 + 16 + r16) * IND + kg * 8);
    const short8* bp2 = (const short8*)(Wt + (size_t)(c0 + 32 + r16) * IND + kg * 8);
    const short8* bp3 = (const short8*)(Wt + (size_t)(c0 + 48 + r16) * IND + kg * 8);

    f32x4 acc[2][4] = {};
    #pragma unroll
    for (int ks = 0; ks < 8; ++ks) {
        float4 x00 = h0p[ks * 8], x01 = h0p[ks * 8 + 1];
        float4 x10 = h1p[ks * 8], x11 = h1p[ks * 8 + 1];
        short8 a0, a1;
        a0[0] = (short)f2bf(x00.x * nm0); a0[1] = (short)f2bf(x00.y * nm0);
        a0[2] = (short)f2bf(x00.z * nm0); a0[3] = (short)f2bf(x00.w * nm0);
        a0[4] = (short)f2bf(x01.x * nm0); a0[5] = (short)f2bf(x01.y * nm0);
        a0[6] = (short)f2bf(x01.z * nm0); a0[7] = (short)f2bf(x01.w * nm0);
        a1[0] = (short)f2bf(x10.x * nm1); a1[1] = (short)f2bf(x10.y * nm1);
        a1[2] = (short)f2bf(x10.z * nm1); a1[3] = (short)f2bf(x10.w * nm1);
        a1[4] = (short)f2bf(x11.x * nm1); a1[5] = (short)f2bf(x11.y * nm1);
        a1[6] = (short)f2bf(x11.z * nm1); a1[7] = (short)f2bf(x11.w * nm1);
        short8 b0 = bp0[ks * 4];
        short8 b1 = bp1[ks * 4];
        short8 b2 = bp2[ks * 4];
        short8 b3 = bp3[ks * 4];
        acc[0][0] = __builtin_amdgcn_mfma_f32_16x16x32_bf16(a0, b0, acc[0][0], 0, 0, 0);
        acc[1][0] = __builtin_amdgcn_mfma_f32_16x16x32_bf16(a1, b0, acc[1][0], 0, 0, 0);
        acc[0][1] = __builtin_amdgcn_mfma_f32_16x16x32_bf16(a0, b1, acc[0][1], 0, 0, 0);
        acc[1][1] = __builtin_amdgcn_mfma_f32_16x16x32_bf16(a1, b1, acc[1][1], 0, 0, 0);
        acc[0][2] = __builtin_amdgcn_mfma_f32_16x16x32_bf16(a0, b2, acc[0][2], 0, 0, 0);
        acc[1][2] = __builtin_amdgcn_mfma_f32_16x16x32_bf16(a1, b2, acc[1][2], 0, 0, 0);
        acc[0][3] = __builtin_amdgcn_mfma_f32_16x16x32_bf16(a0, b3, acc[0][3], 0, 0, 0);
        acc[1][3] = __builtin_amdgcn_mfma_f32_16x16x32_bf16(a1, b3, acc[1][3], 0, 0, 0);
    }

    float asrc[4], adst[4];
    #pragma unroll
    for (int j = 0; j < 4; ++j) {
        asrc[j] = a[wv * 128 + j * 16 + r16];
        adst[j] = a[wv * 128 + 64 + j * 16 + r16];
    }
    #pragma unroll
    for (int mt = 0; mt < 2; ++mt) {
        #pragma unroll
        for (int r = 0; r < 4; ++r) {
            int row = m0 + mt * 16 + kg * 4 + r;
            unsigned short q0 = f2bf(acc[mt][0][r]);
            unsigned short q1 = f2bf(acc[mt][1][r]);
            unsigned short q2 = f2bf(acc[mt][2][r]);
            unsigned short q3 = f2bf(acc[mt][3][r]);
            float ps = bf2f(q0) * asrc[0] + bf2f(q1) * asrc[1] + bf2f(q2) * asrc[2] + bf2f(q3) * asrc[3];
            float pd = bf2f(q0) * adst[0] + bf2f(q1) * adst[1] + bf2f(q2) * adst[2] + bf2f(q3) * adst[3];
            #pragma unroll
            for (int off = 1; off < 16; off <<= 1) {
                ps += __shfl_xor(ps, off);
                pd += __shfl_xor(pd, off);
            }
            if (row < NN) {
                unsigned short* zp = zb + (size_t)row * IND + c0 + r16;
                zp[0]  = q0;
                zp[16] = q1;
                zp[32] = q2;
                zp[48] = q3;
                if (r16 == 0) {
                    ssrc[(row << 2) + wv] = ps;
                    sdst[(row << 2) + wv] = pd;
                }
            }
        }
    }
}

// ---- CSR: histogram (padded counters: one per 64B line) ----
__global__ __launch_bounds__(256) void k_hist(const int* __restrict__ dst, int* __restrict__ cnt) {
    int ed = blockIdx.x * 256 + threadIdx.x;
    if (ed < NE) atomicAdd(&cnt[(size_t)dst[ed] << 4], 1);
}

// ---- parallel scan step 1: per-block sums (strided cnt) ----
__global__ __launch_bounds__(1024) void k_bsum(const int* __restrict__ cnt, int* __restrict__ bsum) {
    __shared__ int ws[16];
    int tid = threadIdx.x, lane = tid & 63, w = tid >> 6;
    int i = blockIdx.x * 1024 + tid;
    int v = (i < NN) ? cnt[(size_t)i << 4] : 0;
    for (int off = 32; off > 0; off >>= 1) v += __shfl_down(v, off);
    if (lane == 0) ws[w] = v;
    __syncthreads();
    if (tid == 0) {
        int s = 0;
        #pragma unroll
        for (int j = 0; j < 16; ++j) s += ws[j];
        bsum[blockIdx.x] = s;
    }
}

// ---- parallel scan step 2: exclusive scan of NB block sums ----
__global__ __launch_bounds__(64) void k_bscan(const int* __restrict__ bsum, int* __restrict__ bsumx) {
    int lane = threadIdx.x;
    int v = (lane < NB) ? bsum[lane] : 0;
    int x = v;
    for (int off = 1; off < 64; off <<= 1) {
        int t = __shfl_up(x, off);
        if (lane >= off) x += t;
    }
    if (lane < NB) bsumx[lane] = x - v;
}

// ---- parallel scan step 3: per-block exclusive scan + block offset (strided cnt/cur) ----
__global__ __launch_bounds__(1024) void k_pscan(const int* __restrict__ cnt, const int* __restrict__ bsumx,
                                                int* __restrict__ rowp, int* __restrict__ cur) {
    __shared__ int wsum[16];
    int tid = threadIdx.x, lane = tid & 63, w = tid >> 6;
    int i = blockIdx.x * 1024 + tid;
    int v = (i < NN) ? cnt[(size_t)i << 4] : 0;
    int x = v;
    for (int off = 1; off < 64; off <<= 1) {
        int t = __shfl_up(x, off);
        if (lane >= off) x += t;
    }
    if (lane == 63) wsum[w] = x;
    __syncthreads();
    if (w == 0 && lane < 16) {
        int y = wsum[lane];
        for (int off = 1; off < 16; off <<= 1) {
            int t = __shfl_up(y, off, 16);
            if (lane >= off) y += t;
        }
        wsum[lane] = y;
    }
    __syncthreads();
    int waveoff = (w == 0) ? 0 : wsum[w - 1];
    int pos = bsumx[blockIdx.x] + waveoff + (x - v);
    if (i < NN) {
        rowp[i] = pos;
        cur[(size_t)i << 4] = pos;
        if (i == NN - 1) rowp[NN] = pos + v;
    }
}

// ---- CSR: scatter edge srcs into dst-sorted order (padded cur) ----
__global__ __launch_bounds__(256) void k_scatter(const int* __restrict__ src, const int* __restrict__ dst,
                                                 int* __restrict__ cur, int* __restrict__ srcs) {
    int ed = blockIdx.x * 256 + threadIdx.x;
    if (ed < NE) {
        int d = dst[ed];
        int p = atomicAdd(&cur[(size_t)d << 4], 1);
        srcs[p] = src[ed];
    }
}

// ---- aggregation: half-wave per node; lane owns 8 dims; 2-way edge unroll ----
__global__ __launch_bounds__(256) void k_agg(const unsigned short* __restrict__ zb, const int* __restrict__ rowp,
                                             const int* __restrict__ srcs, const float* __restrict__ ssrc,
                                             const float* __restrict__ sdst,
                                             const float* __restrict__ h, const float* __restrict__ norm,
                                             float* __restrict__ out) {
    int wv = threadIdx.x >> 6, lane = threadIdx.x & 63;
    int half = lane >> 5;
    int l = lane & 31;
    int n = blockIdx.x * 8 + wv * 2 + half;
    if (n >= NN) return;
    int p0 = rowp[n], p1 = rowp[n + 1];
    int deg = p1 - p0;
    int hd = l >> 3;
    float sd = sdst[(n << 2) + hd];
    float a0 = 0.f, a1 = 0.f, a2 = 0.f, a3 = 0.f;
    float a4 = 0.f, a5 = 0.f, a6 = 0.f, a7 = 0.f;
    float b0 = 0.f, b1 = 0.f, b2 = 0.f, b3 = 0.f;
    float b4 = 0.f, b5 = 0.f, b6 = 0.f, b7 = 0.f;
    float denA = 0.f, denB = 0.f;
    int zoffl = l << 3;
    int i = 0;
    for (; i + 2 <= deg; i += 2) {
        int s0 = srcs[p0 + i];
        int s1 = srcs[p0 + i + 1];
        float w0 = __expf(ssrc[(s0 << 2) + hd] + sd);
        float w1 = __expf(ssrc[(s1 << 2) + hd] + sd);
        uint4 z0 = *(const uint4*)(zb + (s0 << 8) + zoffl);
        uint4 z1 = *(const uint4*)(zb + (s1 << 8) + zoffl);
        a0 += w0 * bf2f((unsigned short)(z0.x & 0xFFFFu));
        a1 += w0 * bf2f((unsigned short)(z0.x >> 16));
        a2 += w0 * bf2f((unsigned short)(z0.y & 0xFFFFu));
        a3 += w0 * bf2f((unsigned short)(z0.y >> 16));
        a4 += w0 * bf2f((unsigned short)(z0.z & 0xFFFFu));
        a5 += w0 * bf2f((unsigned short)(z0.z >> 16));
        a6 += w0 * bf2f((unsigned short)(z0.w & 0xFFFFu));
        a7 += w0 * bf2f((unsigned short)(z0.w >> 16));
        denA += w0;
        b0 += w1 * bf2f((unsigned short)(z1.x & 0xFFFFu));
        b1 += w1 * bf2f((unsigned short)(z1.x >> 16));
        b2 += w1 * bf2f((unsigned short)(z1.y & 0xFFFFu));
        b3 += w1 * bf2f((unsigned short)(z1.y >> 16));
        b4 += w1 * bf2f((unsigned short)(z1.z & 0xFFFFu));
        b5 += w1 * bf2f((unsigned short)(z1.z >> 16));
        b6 += w1 * bf2f((unsigned short)(z1.w & 0xFFFFu));
        b7 += w1 * bf2f((unsigned short)(z1.w >> 16));
        denB += w1;
    }
    if (i < deg) {
        int s0 = srcs[p0 + i];
        float w0 = __expf(ssrc[(s0 << 2) + hd] + sd);
        uint4 z0 = *(const uint4*)(zb + (s0 << 8) + zoffl);
        a0 += w0 * bf2f((unsigned short)(z0.x & 0xFFFFu));
        a1 += w0 * bf2f((unsigned short)(z0.x >> 16));
        a2 += w0 * bf2f((unsigned short)(z0.y & 0xFFFFu));
        a3 += w0 * bf2f((unsigned short)(z0.y >> 16));
        a4 += w0 * bf2f((unsigned short)(z0.z & 0xFFFFu));
        a5 += w0 * bf2f((unsigned short)(z0.z >> 16));
        a6 += w0 * bf2f((unsigned short)(z0.w & 0xFFFFu));
        a7 += w0 * bf2f((unsigned short)(z0.w >> 16));
        denA += w0;
    }
    a0 += b0; a1 += b1; a2 += b2; a3 += b3;
    a4 += b4; a5 += b5; a6 += b6; a7 += b7;
    float den = denA + denB;
    float nm = norm[n];
    float inv = (deg > 0) ? nm / den : 0.f;
    size_t b = (size_t)n * IND + zoffl;
    float4 h0 = *(const float4*)(h + b);
    float4 h1 = *(const float4*)(h + b + 4);
    float4 o0, o1;
    o0.x = h0.x + inv * a0; o0.y = h0.y + inv * a1;
    o0.z = h0.z + inv * a2; o0.w = h0.w + inv * a3;
    o1.x = h1.x + inv * a4; o1.y = h1.y + inv * a5;
    o1.z = h1.z + inv * a6; o1.w = h1.w + inv * a7;
    *(float4*)(out + b) = o0;
    *(float4*)(out + b + 4) = o1;
}

extern "C" void kernel_launch(void* const* d_in, const int* in_sizes, int n_in,
                              void* d_out, int out_size, void* d_ws, size_t ws_size,
                              hipStream_t stream) {
    const float* h    = (const float*)d_in[0];
    const float* e    = (const float*)d_in[1];
    const float* norm = (const float*)d_in[2];
    const int*   src  = (const int*)d_in[3];
    const int*   dst  = (const int*)d_in[4];
    const float* W    = (const float*)d_in[5];
    const float* a    = (const float*)d_in[6];
    float* out = (float*)d_out;

    char* p = (char*)d_ws;
    unsigned short* Wt = (unsigned short*)p; p += 262144;
    unsigned short* zb = (unsigned short*)p; p += 25600000;   // N*256*2
    float* ssrc = (float*)p; p += 800000;
    float* sdst = (float*)p; p += 800000;
    int*   cnt  = (int*)p;   p += 3200000;    // N*16 ints (64B-padded counters)
    int*   rowp = (int*)p;   p += 200192;
    int*   cur  = (int*)p;   p += 3200000;    // N*16 ints (64B-padded counters)
    int*   srcs = (int*)p;   p += 6400000;
    int*   bsum = (int*)p;   p += 4096;
    int*   bsumx= (int*)p;   p += 4096;

    hipMemsetAsync(cnt, 0, NN * 16 * sizeof(int), stream);
    k_wt<<<256, 256, 0, stream>>>(W, Wt);
    k_gmm<<<1563, 256, 0, stream>>>(h, norm, Wt, a, zb, ssrc, sdst);
    k_hist<<<6250, 256, 0, stream>>>(dst, cnt);
    k_bsum<<<NB, 1024, 0, stream>>>(cnt, bsum);
    k_bscan<<<1, 64, 0, stream>>>(bsum, bsumx);
    k_pscan<<<NB, 1024, 0, stream>>>(cnt, bsumx, rowp, cur);
    k_scatter<<<6250, 256, 0, stream>>>(src, dst, cur, srcs);
    k_agg<<<6250, 256, 0, stream>>>(zb, rowp, srcs, ssrc, sdst, h, norm, out);
    hipMemcpyAsync(out + (size_t)NN * IND, e, NE * sizeof(float), hipMemcpyDeviceToDevice, stream);
}

// Round 15
// 311.353 us; speedup vs baseline: 2.4342x; 1.2544x over previous
//
#include <hip/hip_runtime.h>

#define NN 50000
#define NE 1600000
#define IND 256
#define OUTD 64
#define NH 4
#define EPB 4096
#define NBLKP 391   // ceil(NE/EPB)
#define NBUCK 196   // ceil(NN/256)

typedef __attribute__((ext_vector_type(8))) short short8;
typedef __attribute__((ext_vector_type(4))) float f32x4;

__device__ __forceinline__ unsigned short f2bf(float x) {
    unsigned int u = __float_as_uint(x);
    u = (u + 0x7FFFu + ((u >> 16) & 1u)) >> 16;   // RNE
    return (unsigned short)u;
}
__device__ __forceinline__ float bf2f(unsigned short u) {
    return __uint_as_float((unsigned int)u << 16);
}

// ---- Wt[c][k] = bf16(W[c>>6][k][c&63]) ----
__global__ __launch_bounds__(256) void k_wt(const float* __restrict__ W, unsigned short* __restrict__ Wt) {
    int t = blockIdx.x * 256 + threadIdx.x;
    int c = t >> 8, k = t & 255;
    Wt[t] = f2bf(W[(c >> 6) * IND * OUTD + k * OUTD + (c & 63)]);
}

// ---- fused: zb = bf16((h*norm) @ Wt^T) via MFMA + inline conv + s_src/s_dst epilogue ----
__global__ __launch_bounds__(256) void k_gmm(const float* __restrict__ h, const float* __restrict__ norm,
                                             const unsigned short* __restrict__ Wt, const float* __restrict__ a,
                                             unsigned short* __restrict__ zb,
                                             float* __restrict__ ssrc, float* __restrict__ sdst) {
    const int lane = threadIdx.x & 63;
    const int wv = threadIdx.x >> 6;          // head index
    const int m0 = blockIdx.x * 32;
    const int c0 = wv * 64;
    const int r16 = lane & 15, kg = lane >> 4;

    int rowA0 = m0 + r16;      if (rowA0 > NN - 1) rowA0 = NN - 1;
    int rowA1 = m0 + 16 + r16; if (rowA1 > NN - 1) rowA1 = NN - 1;
    float nm0 = norm[rowA0], nm1 = norm[rowA1];
    const float4* h0p = (const float4*)(h + (size_t)rowA0 * IND + kg * 8);
    const float4* h1p = (const float4*)(h + (size_t)rowA1 * IND + kg * 8);
    const short8* bp0 = (const short8*)(Wt + (size_t)(c0 +  0 + r16) * IND + kg * 8);
    const short8* bp1 = (const short8*)(Wt + (size_t)(c0 + 16 + r16) * IND + kg * 8);
    const short8* bp2 = (const short8*)(Wt + (size_t)(c0 + 32 + r16) * IND + kg * 8);
    const short8* bp3 = (const short8*)(Wt + (size_t)(c0 + 48 + r16) * IND + kg * 8);

    f32x4 acc[2][4] = {};
    #pragma unroll
    for (int ks = 0; ks < 8; ++ks) {
        float4 x00 = h0p[ks * 8], x01 = h0p[ks * 8 + 1];
        float4 x10 = h1p[ks * 8], x11 = h1p[ks * 8 + 1];
        short8 a0, a1;
        a0[0] = (short)f2bf(x00.x * nm0); a0[1] = (short)f2bf(x00.y * nm0);
        a0[2] = (short)f2bf(x00.z * nm0); a0[3] = (short)f2bf(x00.w * nm0);
        a0[4] = (short)f2bf(x01.x * nm0); a0[5] = (short)f2bf(x01.y * nm0);
        a0[6] = (short)f2bf(x01.z * nm0); a0[7] = (short)f2bf(x01.w * nm0);
        a1[0] = (short)f2bf(x10.x * nm1); a1[1] = (short)f2bf(x10.y * nm1);
        a1[2] = (short)f2bf(x10.z * nm1); a1[3] = (short)f2bf(x10.w * nm1);
        a1[4] = (short)f2bf(x11.x * nm1); a1[5] = (short)f2bf(x11.y * nm1);
        a1[6] = (short)f2bf(x11.z * nm1); a1[7] = (short)f2bf(x11.w * nm1);
        short8 b0 = bp0[ks * 4];
        short8 b1 = bp1[ks * 4];
        short8 b2 = bp2[ks * 4];
        short8 b3 = bp3[ks * 4];
        acc[0][0] = __builtin_amdgcn_mfma_f32_16x16x32_bf16(a0, b0, acc[0][0], 0, 0, 0);
        acc[1][0] = __builtin_amdgcn_mfma_f32_16x16x32_bf16(a1, b0, acc[1][0], 0, 0, 0);
        acc[0][1] = __builtin_amdgcn_mfma_f32_16x16x32_bf16(a0, b1, acc[0][1], 0, 0, 0);
        acc[1][1] = __builtin_amdgcn_mfma_f32_16x16x32_bf16(a1, b1, acc[1][1], 0, 0, 0);
        acc[0][2] = __builtin_amdgcn_mfma_f32_16x16x32_bf16(a0, b2, acc[0][2], 0, 0, 0);
        acc[1][2] = __builtin_amdgcn_mfma_f32_16x16x32_bf16(a1, b2, acc[1][2], 0, 0, 0);
        acc[0][3] = __builtin_amdgcn_mfma_f32_16x16x32_bf16(a0, b3, acc[0][3], 0, 0, 0);
        acc[1][3] = __builtin_amdgcn_mfma_f32_16x16x32_bf16(a1, b3, acc[1][3], 0, 0, 0);
    }

    float asrc[4], adst[4];
    #pragma unroll
    for (int j = 0; j < 4; ++j) {
        asrc[j] = a[wv * 128 + j * 16 + r16];
        adst[j] = a[wv * 128 + 64 + j * 16 + r16];
    }
    #pragma unroll
    for (int mt = 0; mt < 2; ++mt) {
        #pragma unroll
        for (int r = 0; r < 4; ++r) {
            int row = m0 + mt * 16 + kg * 4 + r;
            unsigned short q0 = f2bf(acc[mt][0][r]);
            unsigned short q1 = f2bf(acc[mt][1][r]);
            unsigned short q2 = f2bf(acc[mt][2][r]);
            unsigned short q3 = f2bf(acc[mt][3][r]);
            float ps = bf2f(q0) * asrc[0] + bf2f(q1) * asrc[1] + bf2f(q2) * asrc[2] + bf2f(q3) * asrc[3];
            float pd = bf2f(q0) * adst[0] + bf2f(q1) * adst[1] + bf2f(q2) * adst[2] + bf2f(q3) * adst[3];
            #pragma unroll
            for (int off = 1; off < 16; off <<= 1) {
                ps += __shfl_xor(ps, off);
                pd += __shfl_xor(pd, off);
            }
            if (row < NN) {
                unsigned short* zp = zb + (size_t)row * IND + c0 + r16;
                zp[0]  = q0;
                zp[16] = q1;
                zp[32] = q2;
                zp[48] = q3;
                if (r16 == 0) {
                    ssrc[(row << 2) + wv] = ps;
                    sdst[(row << 2) + wv] = pd;
                }
            }
        }
    }
}

// ---- partition step 1: per-block histogram over 196 coarse buckets (dst>>8) ----
__global__ __launch_bounds__(256) void k_phist(const int* __restrict__ dst, int* __restrict__ bh) {
    __shared__ int lh[NBUCK];
    int tid = threadIdx.x;
    if (tid < NBUCK) lh[tid] = 0;
    __syncthreads();
    int base = blockIdx.x * EPB;
    for (int i = tid; i < EPB; i += 256) {
        int ed = base + i;
        if (ed < NE) atomicAdd(&lh[dst[ed] >> 8], 1);
    }
    __syncthreads();
    if (tid < NBUCK) bh[blockIdx.x * NBUCK + tid] = lh[tid];
}

// ---- partition step 2: column scan of bh -> per-(block,bucket) run offsets + bstart ----
__global__ __launch_bounds__(256) void k_poff(const int* __restrict__ bh, int* __restrict__ goff,
                                              int* __restrict__ bstart) {
    __shared__ int wsum[4];
    int t = threadIdx.x;
    int col = 0;
    if (t < NBUCK) {
        int b = 0;
        for (; b + 4 <= NBLKP; b += 4) {
            int v0 = bh[(b + 0) * NBUCK + t];
            int v1 = bh[(b + 1) * NBUCK + t];
            int v2 = bh[(b + 2) * NBUCK + t];
            int v3 = bh[(b + 3) * NBUCK + t];
            goff[(b + 0) * NBUCK + t] = col; col += v0;
            goff[(b + 1) * NBUCK + t] = col; col += v1;
            goff[(b + 2) * NBUCK + t] = col; col += v2;
            goff[(b + 3) * NBUCK + t] = col; col += v3;
        }
        for (; b < NBLKP; ++b) {
            int v = bh[b * NBUCK + t];
            goff[b * NBUCK + t] = col; col += v;
        }
    }
    // exclusive scan of col across threads
    int lane = t & 63, w = t >> 6;
    int x = col;
    for (int off = 1; off < 64; off <<= 1) {
        int tmp = __shfl_up(x, off);
        if (lane >= off) x += tmp;
    }
    if (lane == 63) wsum[w] = x;
    __syncthreads();
    int waveoff = 0;
    for (int j = 0; j < w; ++j) waveoff += wsum[j];
    int excl = waveoff + x - col;
    if (t < NBUCK) {
        bstart[t] = excl;
        int b = 0;
        for (; b + 4 <= NBLKP; b += 4) {
            goff[(b + 0) * NBUCK + t] += excl;
            goff[(b + 1) * NBUCK + t] += excl;
            goff[(b + 2) * NBUCK + t] += excl;
            goff[(b + 3) * NBUCK + t] += excl;
        }
        for (; b < NBLKP; ++b) goff[b * NBUCK + t] += excl;
    }
    if (t == 0) bstart[NBUCK] = NE;
}

// ---- partition step 3: append edges into reserved per-(block,bucket) runs ----
__global__ __launch_bounds__(256) void k_pscat(const int* __restrict__ src, const int* __restrict__ dst,
                                               const int* __restrict__ goff,
                                               unsigned long long* __restrict__ tmp) {
    __shared__ int lcur[NBUCK];
    int tid = threadIdx.x;
    if (tid < NBUCK) lcur[tid] = 0;
    __syncthreads();
    int base = blockIdx.x * EPB;
    const int* go = goff + blockIdx.x * NBUCK;
    for (int i = tid; i < EPB; i += 256) {
        int ed = base + i;
        if (ed < NE) {
            int d = dst[ed];
            int bin = d >> 8;
            int r = atomicAdd(&lcur[bin], 1);
            tmp[go[bin] + r] = ((unsigned long long)(unsigned int)d << 32) | (unsigned int)src[ed];
        }
    }
}

// ---- partition step 4: per-bucket local counting sort -> srcs (block-exclusive region) + rowp ----
__global__ __launch_bounds__(256) void k_lsort(const unsigned long long* __restrict__ tmp,
                                               const int* __restrict__ bstart,
                                               int* __restrict__ rowp, int* __restrict__ srcs) {
    __shared__ int lh[256], lcur[256], wsum[4];
    int b = blockIdx.x, tid = threadIdx.x;
    int base = bstart[b], cnt = bstart[b + 1] - base;
    lh[tid] = 0;
    __syncthreads();
    for (int i = tid; i < cnt; i += 256) {
        int dloc = (int)(tmp[base + i] >> 32) & 255;
        atomicAdd(&lh[dloc], 1);
    }
    __syncthreads();
    int lane = tid & 63, w = tid >> 6;
    int v = lh[tid];
    int x = v;
    for (int off = 1; off < 64; off <<= 1) {
        int t2 = __shfl_up(x, off);
        if (lane >= off) x += t2;
    }
    if (lane == 63) wsum[w] = x;
    __syncthreads();
    int waveoff = 0;
    for (int j = 0; j < w; ++j) waveoff += wsum[j];
    int excl = waveoff + x - v;
    lcur[tid] = excl;
    int d = (b << 8) + tid;
    if (d < NN) rowp[d] = base + excl;
    if (b == NBUCK - 1 && tid == 0) rowp[NN] = NE;
    __syncthreads();
    for (int i = tid; i < cnt; i += 256) {
        unsigned long long rec = tmp[base + i];
        int dloc = (int)(rec >> 32) & 255;
        int p = atomicAdd(&lcur[dloc], 1);
        srcs[base + p] = (int)(rec & 0xFFFFFFFFu);
    }
}

// ---- aggregation: half-wave per node; lane owns 8 dims; 2-way edge unroll ----
__global__ __launch_bounds__(256) void k_agg(const unsigned short* __restrict__ zb, const int* __restrict__ rowp,
                                             const int* __restrict__ srcs, const float* __restrict__ ssrc,
                                             const float* __restrict__ sdst,
                                             const float* __restrict__ h, const float* __restrict__ norm,
                                             float* __restrict__ out) {
    int wv = threadIdx.x >> 6, lane = threadIdx.x & 63;
    int half = lane >> 5;
    int l = lane & 31;
    int n = blockIdx.x * 8 + wv * 2 + half;
    if (n >= NN) return;
    int p0 = rowp[n], p1 = rowp[n + 1];
    int deg = p1 - p0;
    int hd = l >> 3;
    float sd = sdst[(n << 2) + hd];
    float a0 = 0.f, a1 = 0.f, a2 = 0.f, a3 = 0.f;
    float a4 = 0.f, a5 = 0.f, a6 = 0.f, a7 = 0.f;
    float b0 = 0.f, b1 = 0.f, b2 = 0.f, b3 = 0.f;
    float b4 = 0.f, b5 = 0.f, b6 = 0.f, b7 = 0.f;
    float denA = 0.f, denB = 0.f;
    int zoffl = l << 3;
    int i = 0;
    for (; i + 2 <= deg; i += 2) {
        int s0 = srcs[p0 + i];
        int s1 = srcs[p0 + i + 1];
        float w0 = __expf(ssrc[(s0 << 2) + hd] + sd);
        float w1 = __expf(ssrc[(s1 << 2) + hd] + sd);
        uint4 z0 = *(const uint4*)(zb + (s0 << 8) + zoffl);
        uint4 z1 = *(const uint4*)(zb + (s1 << 8) + zoffl);
        a0 += w0 * bf2f((unsigned short)(z0.x & 0xFFFFu));
        a1 += w0 * bf2f((unsigned short)(z0.x >> 16));
        a2 += w0 * bf2f((unsigned short)(z0.y & 0xFFFFu));
        a3 += w0 * bf2f((unsigned short)(z0.y >> 16));
        a4 += w0 * bf2f((unsigned short)(z0.z & 0xFFFFu));
        a5 += w0 * bf2f((unsigned short)(z0.z >> 16));
        a6 += w0 * bf2f((unsigned short)(z0.w & 0xFFFFu));
        a7 += w0 * bf2f((unsigned short)(z0.w >> 16));
        denA += w0;
        b0 += w1 * bf2f((unsigned short)(z1.x & 0xFFFFu));
        b1 += w1 * bf2f((unsigned short)(z1.x >> 16));
        b2 += w1 * bf2f((unsigned short)(z1.y & 0xFFFFu));
        b3 += w1 * bf2f((unsigned short)(z1.y >> 16));
        b4 += w1 * bf2f((unsigned short)(z1.z & 0xFFFFu));
        b5 += w1 * bf2f((unsigned short)(z1.z >> 16));
        b6 += w1 * bf2f((unsigned short)(z1.w & 0xFFFFu));
        b7 += w1 * bf2f((unsigned short)(z1.w >> 16));
        denB += w1;
    }
    if (i < deg) {
        int s0 = srcs[p0 + i];
        float w0 = __expf(ssrc[(s0 << 2) + hd] + sd);
        uint4 z0 = *(const uint4*)(zb + (s0 << 8) + zoffl);
        a0 += w0 * bf2f((unsigned short)(z0.x & 0xFFFFu));
        a1 += w0 * bf2f((unsigned short)(z0.x >> 16));
        a2 += w0 * bf2f((unsigned short)(z0.y & 0xFFFFu));
        a3 += w0 * bf2f((unsigned short)(z0.y >> 16));
        a4 += w0 * bf2f((unsigned short)(z0.z & 0xFFFFu));
        a5 += w0 * bf2f((unsigned short)(z0.z >> 16));
        a6 += w0 * bf2f((unsigned short)(z0.w & 0xFFFFu));
        a7 += w0 * bf2f((unsigned short)(z0.w >> 16));
        denA += w0;
    }
    a0 += b0; a1 += b1; a2 += b2; a3 += b3;
    a4 += b4; a5 += b5; a6 += b6; a7 += b7;
    float den = denA + denB;
    float nm = norm[n];
    float inv = (deg > 0) ? nm / den : 0.f;
    size_t bofs = (size_t)n * IND + zoffl;
    float4 h0 = *(const float4*)(h + bofs);
    float4 h1 = *(const float4*)(h + bofs + 4);
    float4 o0, o1;
    o0.x = h0.x + inv * a0; o0.y = h0.y + inv * a1;
    o0.z = h0.z + inv * a2; o0.w = h0.w + inv * a3;
    o1.x = h1.x + inv * a4; o1.y = h1.y + inv * a5;
    o1.z = h1.z + inv * a6; o1.w = h1.w + inv * a7;
    *(float4*)(out + bofs) = o0;
    *(float4*)(out + bofs + 4) = o1;
}

extern "C" void kernel_launch(void* const* d_in, const int* in_sizes, int n_in,
                              void* d_out, int out_size, void* d_ws, size_t ws_size,
                              hipStream_t stream) {
    const float* h    = (const float*)d_in[0];
    const float* e    = (const float*)d_in[1];
    const float* norm = (const float*)d_in[2];
    const int*   src  = (const int*)d_in[3];
    const int*   dst  = (const int*)d_in[4];
    const float* W    = (const float*)d_in[5];
    const float* a    = (const float*)d_in[6];
    float* out = (float*)d_out;

    char* p = (char*)d_ws;
    unsigned short* Wt = (unsigned short*)p; p += 262144;
    unsigned short* zb = (unsigned short*)p; p += 25600000;   // N*256*2
    float* ssrc = (float*)p; p += 800000;
    float* sdst = (float*)p; p += 800000;
    int*   rowp = (int*)p;   p += 200192;
    int*   srcs = (int*)p;   p += 6400000;
    int*   bh   = (int*)p;   p += 307200;     // NBLKP*NBUCK ints
    int*   goff = (int*)p;   p += 307200;
    int*   bstart = (int*)p; p += 4096;
    unsigned long long* tmp = (unsigned long long*)p; p += 12800000;  // NE*8

    k_wt<<<256, 256, 0, stream>>>(W, Wt);
    k_gmm<<<1563, 256, 0, stream>>>(h, norm, Wt, a, zb, ssrc, sdst);
    k_phist<<<NBLKP, 256, 0, stream>>>(dst, bh);
    k_poff<<<1, 256, 0, stream>>>(bh, goff, bstart);
    k_pscat<<<NBLKP, 256, 0, stream>>>(src, dst, goff, tmp);
    k_lsort<<<NBUCK, 256, 0, stream>>>(tmp, bstart, rowp, srcs);
    k_agg<<<6250, 256, 0, stream>>>(zb, rowp, srcs, ssrc, sdst, h, norm, out);
    hipMemcpyAsync(out + (size_t)NN * IND, e, NE * sizeof(float), hipMemcpyDeviceToDevice, stream);
}